// Round 17
// baseline (274.493 us; speedup 1.0000x reference)
//
#include <hip/hip_runtime.h>

#define HID 64
#define INDIM 128
#define NBUCK 256          // bucket = dst >> 9  (512 nodes/bucket)
#define EBUF_PER 10240     // fixed ebuf region per bucket (avg fill 8192, 22 sigma)
#define CHUNK 4096         // edges per binA block

typedef unsigned short ushort_t;
typedef unsigned int uint_t;
typedef float floatx2 __attribute__((ext_vector_type(2)));

__device__ __forceinline__ float softplusf(float x) {
    return fmaxf(x, 0.f) + log1pf(expf(-fabsf(x)));
}
__device__ __forceinline__ ushort_t f2bf(float f) {
    union { float f; uint_t i; } c; c.f = f;
    uint_t u = c.i;
    u += 0x7FFFu + ((u >> 16) & 1u);
    return (ushort_t)(u >> 16);
}
__device__ __forceinline__ float lo_bf(uint_t u) {
    union { uint_t i; float f; } c; c.i = u << 16; return c.f;
}
__device__ __forceinline__ float hi_bf(uint_t u) {
    union { uint_t i; float f; } c; c.i = u & 0xFFFF0000u; return c.f;
}
__device__ __forceinline__ float dec_norm(uint_t x) {
    union { uint_t i; float f; } c; c.i = (x >> 17) << 16; return c.f;
}

// ===== K1: fused [binA (blocks 0..nbA) | gemm (rest)] ======================
// binA: LDS-binned bucket scatter into ebuf + global degree histogram.
// gemm: R15's proven 64-row acc[4][4] version (66.5KB LDS, ILP-rich).
__global__ __launch_bounds__(256) void k_fused(const float* __restrict__ x,
                                               const float* __restrict__ W,
                                               const int* __restrict__ src,
                                               const int* __restrict__ dst,
                                               uint_t* __restrict__ Hq,
                                               int* __restrict__ cnt,
                                               int* __restrict__ bcur,
                                               int2* __restrict__ ebuf,
                                               int N, int E, int nbA) {
    __shared__ char lds[66560];
    int tid = threadIdx.x;

    if ((int)blockIdx.x < nbA) {
        // ---------------- binA ----------------
        int2* stage  = (int2*)lds;               // 32768
        int* lcnt    = (int*)(lds + 32768);
        int* binSt   = (int*)(lds + 33792);
        int* lofs    = (int*)(lds + 34816);
        int* gofs    = (int*)(lds + 35840);
        int* scn     = (int*)(lds + 36864);      // ..37888
        int base = blockIdx.x * CHUNK;

        lcnt[tid] = 0;
        __syncthreads();

        int sv[16], dv[16];
#pragma unroll
        for (int i = 0; i < 16; i++) {
            int e = base + i * 256 + tid;
            if (e < E) { sv[i] = src[e]; dv[i] = dst[e]; }
            else dv[i] = -1;
        }
#pragma unroll
        for (int i = 0; i < 16; i++) {
            if (dv[i] >= 0) {
                atomicAdd(&lcnt[dv[i] >> 9], 1);
                atomicAdd(&cnt[dv[i]], 1);       // global degree histogram
            }
        }
        __syncthreads();

        scn[tid] = lcnt[tid];
        __syncthreads();
        for (int off = 1; off < NBUCK; off <<= 1) {
            int v = (tid >= off) ? scn[tid - off] : 0;
            __syncthreads();
            scn[tid] += v;
            __syncthreads();
        }
        binSt[tid] = scn[tid] - lcnt[tid];
        lofs[tid] = binSt[tid];
        __syncthreads();

#pragma unroll
        for (int i = 0; i < 16; i++) {
            if (dv[i] >= 0) {
                int b = dv[i] >> 9;
                int p = atomicAdd(&lofs[b], 1);
                stage[p] = make_int2(sv[i], dv[i]);
            }
        }
        __syncthreads();

        if (lcnt[tid] > 0)
            gofs[tid] = tid * EBUF_PER + atomicAdd(&bcur[tid], lcnt[tid]);
        __syncthreads();

        int total = (base + CHUNK <= E) ? CHUNK : (E > base ? E - base : 0);
        for (int idx = tid; idx < total; idx += 256) {
            int2 v = stage[idx];
            int b = v.y >> 9;
            ebuf[gofs[b] + (idx - binSt[b])] = v;
        }
    } else {
        // ---------------- gemm: 64 rows, acc[4][4] ----------------
        float* Xs = (float*)lds;                 // 64*132*4 = 33792
        float* Ws = (float*)(lds + 33792);       // 32768 -> total 66560
        int row0 = ((int)blockIdx.x - nbA) * 64;

        const float4* W4 = (const float4*)W;
        float4* Ws4 = (float4*)Ws;
#pragma unroll
        for (int i = 0; i < 8; i++) Ws4[tid + 256 * i] = W4[tid + 256 * i];

#pragma unroll
        for (int i = 0; i < 8; i++) {
            int j = tid + 256 * i;
            int r = j >> 5, c4 = j & 31;
            int row = row0 + r;
            float4 v = make_float4(0.f, 0.f, 0.f, 0.f);
            if (row < N) v = *(const float4*)(x + (size_t)row * INDIM + c4 * 4);
            *(float4*)(&Xs[r * 132 + c4 * 4]) = v;
        }
        __syncthreads();

        int tx = tid & 15;
        int ty = tid >> 4;
        float acc[4][4] = {};
        const float* xa = &Xs[(ty * 4) * 132];
#pragma unroll 4
        for (int k = 0; k < 128; k++) {
            float4 b = *(const float4*)(&Ws[k * 64 + tx * 4]);
#pragma unroll
            for (int i = 0; i < 4; i++) {
                float a = xa[i * 132 + k];
                acc[i][0] = fmaf(a, b.x, acc[i][0]);
                acc[i][1] = fmaf(a, b.y, acc[i][1]);
                acc[i][2] = fmaf(a, b.z, acc[i][2]);
                acc[i][3] = fmaf(a, b.w, acc[i][3]);
            }
        }
#pragma unroll
        for (int i = 0; i < 4; i++) {
            int row = row0 + ty * 4 + i;
            if (row < N) {
                uint_t u = 0;
                u = __builtin_amdgcn_cvt_pk_fp8_f32(acc[i][0], acc[i][1], u, false);
                u = __builtin_amdgcn_cvt_pk_fp8_f32(acc[i][2], acc[i][3], u, true);
                Hq[(size_t)row * 16 + tx] = u;
            }
        }
    }
}

// ===== K2: dinv[i] = rsqrt(cnt[i]+1) =======================================
__global__ __launch_bounds__(256) void k_dinv(const int* __restrict__ cnt,
                                              float* __restrict__ dinv, int N) {
    int i = blockIdx.x * 256 + threadIdx.x;
    if (i < N) dinv[i] = rsqrtf((float)cnt[i] + 1.0f);
}

// ===== K3: binB (merged) — rowptr/dinv-local + placement w/ packed norm ====
// csrS[j] = { s | norm15<<17 , perm[s] }; norm15 = top 15 bits of f32 (no sign)
__global__ __launch_bounds__(256) void k_binB(const int2* __restrict__ ebuf,
                                              const int* __restrict__ bcur,
                                              const int* __restrict__ perm,
                                              const float* __restrict__ dinvg,
                                              int2* __restrict__ csrS,
                                              int* __restrict__ rowptr,
                                              int N, int E) {
    __shared__ int bb[NBUCK];
    __shared__ int sc[256];
    __shared__ int ldeg[512];
    __shared__ int lcur[512];
    __shared__ float ldinv[512];
    int tid = threadIdx.x;
    int b = blockIdx.x;

    bb[tid] = bcur[tid];
    __syncthreads();
    for (int off = 1; off < NBUCK; off <<= 1) {
        int v = (tid >= off) ? bb[tid - off] : 0;
        __syncthreads();
        bb[tid] += v;
        __syncthreads();
    }
    int bucketBase = (b == 0) ? 0 : bb[b - 1];

    ldeg[tid] = 0;
    ldeg[tid + 256] = 0;
    __syncthreads();

    int start = b * EBUF_PER;
    int cb = bcur[b];
    for (int i = start + tid; i < start + cb; i += 256)
        atomicAdd(&ldeg[ebuf[i].y & 511], 1);
    __syncthreads();

    int d0 = ldeg[2 * tid], d1 = ldeg[2 * tid + 1];
    int s2 = d0 + d1;
    sc[tid] = s2;
    __syncthreads();
    for (int off = 1; off < 256; off <<= 1) {
        int v = (tid >= off) ? sc[tid - off] : 0;
        __syncthreads();
        sc[tid] += v;
        __syncthreads();
    }
    int ex = sc[tid] - s2;
    int n0 = (b << 9) + 2 * tid, n1 = n0 + 1;
    int r0 = bucketBase + ex, r1 = r0 + d0;
    if (n0 < N) { rowptr[n0] = r0; lcur[2 * tid] = r0; ldinv[2 * tid] = rsqrtf((float)(d0 + 1)); }
    if (n1 < N) { rowptr[n1] = r1; lcur[2 * tid + 1] = r1; ldinv[2 * tid + 1] = rsqrtf((float)(d1 + 1)); }
    if (b == 0 && tid == 0) rowptr[N] = E;
    __syncthreads();

    for (int i = start + tid; i < start + cb; i += 256) {
        int2 v = ebuf[i];
        int s = v.x, dl = v.y & 511;
        int j = atomicAdd(&lcur[dl], 1);
        float nm = dinvg[s] * ldinv[dl];
        union { float f; uint_t u; } cu; cu.f = nm;
        uint_t nb = (cu.u >> 16) & 0x7FFFu;
        csrS[j] = make_int2((int)((uint_t)s | (nb << 17)), perm[s]);
    }
}

// ===== K4: gather — fp8, slot layout, 3-stage pipeline, packed norms =======
// lane = (slot, sub16); slot = (pair, isneg). Each H load = 4 rows x 64 B.
__global__ __launch_bounds__(256) void k_gather(const uint_t* __restrict__ Hq,
                                                const int* __restrict__ rowptr,
                                                const int2* __restrict__ csrS,
                                                const int* __restrict__ perm,
                                                const float* __restrict__ dinv,
                                                const float* __restrict__ b,
                                                const float* __restrict__ a,
                                                ushort_t* __restrict__ posb,
                                                ushort_t* __restrict__ negb,
                                                float* __restrict__ sumvec, int N) {
    int tid = threadIdx.x;
    int lane = tid & 63;
    int slot = lane >> 4;
    int sub = lane & 15;
    int isneg = slot & 1;
    int pair = slot >> 1;
    int wid = (blockIdx.x * 256 + tid) >> 6;
    int nw = gridDim.x * 4;
    float4 b4 = ((const float4*)b)[sub];
    float4 a4 = ((const float4*)a)[sub];
    float s0 = 0.f, s1 = 0.f, s2 = 0.f, s3 = 0.f;

    for (int n = wid; n < N; n += nw) {
        float dv = dinv[n];
        float w2 = dv * dv;
        int beg = rowptr[n], end = rowptr[n + 1];
        float a0 = 0.f, a1 = 0.f, a2 = 0.f, a3 = 0.f;

        // ---- prologue: csr iter0 (cA) + iter1 (cB); H values iter0 (uc) ----
        int e0 = beg + pair, e1 = beg + 2 + pair, e2 = beg + 4 + pair, e3 = beg + 6 + pair;
        int2 cA0 = (e0 < end) ? csrS[e0] : make_int2(0, 0);
        int2 cA1 = (e1 < end) ? csrS[e1] : make_int2(0, 0);
        int2 cA2 = (e2 < end) ? csrS[e2] : make_int2(0, 0);
        int2 cA3 = (e3 < end) ? csrS[e3] : make_int2(0, 0);
        int f0 = e0 + 8, f1 = e1 + 8, f2 = e2 + 8, f3 = e3 + 8;
        int2 cB0 = (f0 < end) ? csrS[f0] : make_int2(0, 0);
        int2 cB1 = (f1 < end) ? csrS[f1] : make_int2(0, 0);
        int2 cB2 = (f2 < end) ? csrS[f2] : make_int2(0, 0);
        int2 cB3 = (f3 < end) ? csrS[f3] : make_int2(0, 0);
        uint_t uc0 = Hq[(size_t)(isneg ? (uint_t)cA0.y : ((uint_t)cA0.x & 0x1FFFFu)) * 16 + sub];
        uint_t uc1 = Hq[(size_t)(isneg ? (uint_t)cA1.y : ((uint_t)cA1.x & 0x1FFFFu)) * 16 + sub];
        uint_t uc2 = Hq[(size_t)(isneg ? (uint_t)cA2.y : ((uint_t)cA2.x & 0x1FFFFu)) * 16 + sub];
        uint_t uc3 = Hq[(size_t)(isneg ? (uint_t)cA3.y : ((uint_t)cA3.x & 0x1FFFFu)) * 16 + sub];

        for (int j = beg; j < end; j += 8) {
            // stage 1: csr two iters ahead
            int g0 = j + 16 + pair, g1 = j + 18 + pair, g2 = j + 20 + pair, g3 = j + 22 + pair;
            int2 cC0 = (g0 < end) ? csrS[g0] : make_int2(0, 0);
            int2 cC1 = (g1 < end) ? csrS[g1] : make_int2(0, 0);
            int2 cC2 = (g2 < end) ? csrS[g2] : make_int2(0, 0);
            int2 cC3 = (g3 < end) ? csrS[g3] : make_int2(0, 0);
            // stage 2: H loads one iter ahead (rows from cB)
            uint_t un0 = Hq[(size_t)(isneg ? (uint_t)cB0.y : ((uint_t)cB0.x & 0x1FFFFu)) * 16 + sub];
            uint_t un1 = Hq[(size_t)(isneg ? (uint_t)cB1.y : ((uint_t)cB1.x & 0x1FFFFu)) * 16 + sub];
            uint_t un2 = Hq[(size_t)(isneg ? (uint_t)cB2.y : ((uint_t)cB2.x & 0x1FFFFu)) * 16 + sub];
            uint_t un3 = Hq[(size_t)(isneg ? (uint_t)cB3.y : ((uint_t)cB3.x & 0x1FFFFu)) * 16 + sub];
            // stage 3: consume iter j (H in uc, norms decoded from cA)
            float mA0 = dec_norm((uint_t)cA0.x);
            float mA1 = dec_norm((uint_t)cA1.x);
            float mA2 = dec_norm((uint_t)cA2.x);
            float mA3 = dec_norm((uint_t)cA3.x);
            floatx2 lo, hi;
            lo = __builtin_amdgcn_cvt_pk_f32_fp8(uc0, false);
            hi = __builtin_amdgcn_cvt_pk_f32_fp8(uc0, true);
            a0 = fmaf(lo.x, mA0, a0); a1 = fmaf(lo.y, mA0, a1);
            a2 = fmaf(hi.x, mA0, a2); a3 = fmaf(hi.y, mA0, a3);
            lo = __builtin_amdgcn_cvt_pk_f32_fp8(uc1, false);
            hi = __builtin_amdgcn_cvt_pk_f32_fp8(uc1, true);
            a0 = fmaf(lo.x, mA1, a0); a1 = fmaf(lo.y, mA1, a1);
            a2 = fmaf(hi.x, mA1, a2); a3 = fmaf(hi.y, mA1, a3);
            lo = __builtin_amdgcn_cvt_pk_f32_fp8(uc2, false);
            hi = __builtin_amdgcn_cvt_pk_f32_fp8(uc2, true);
            a0 = fmaf(lo.x, mA2, a0); a1 = fmaf(lo.y, mA2, a1);
            a2 = fmaf(hi.x, mA2, a2); a3 = fmaf(hi.y, mA2, a3);
            lo = __builtin_amdgcn_cvt_pk_f32_fp8(uc3, false);
            hi = __builtin_amdgcn_cvt_pk_f32_fp8(uc3, true);
            a0 = fmaf(lo.x, mA3, a0); a1 = fmaf(lo.y, mA3, a1);
            a2 = fmaf(hi.x, mA3, a2); a3 = fmaf(hi.y, mA3, a3);
            // rotate
            cA0 = cB0; cA1 = cB1; cA2 = cB2; cA3 = cB3;
            cB0 = cC0; cB1 = cC1; cB2 = cC2; cB3 = cC3;
            uc0 = un0; uc1 = un1; uc2 = un2; uc3 = un3;
        }
        a0 += __shfl_xor(a0, 32);
        a1 += __shfl_xor(a1, 32);
        a2 += __shfl_xor(a2, 32);
        a3 += __shfl_xor(a3, 32);
        int selfrow = isneg ? perm[n] : n;
        uint_t us = Hq[(size_t)selfrow * 16 + sub];
        floatx2 slo = __builtin_amdgcn_cvt_pk_f32_fp8(us, false);
        floatx2 shi = __builtin_amdgcn_cvt_pk_f32_fp8(us, true);
        float v0 = fmaf(slo.x, w2, a0) + b4.x;
        float v1 = fmaf(slo.y, w2, a1) + b4.y;
        float v2 = fmaf(shi.x, w2, a2) + b4.z;
        float v3 = fmaf(shi.y, w2, a3) + b4.w;
        v0 = v0 > 0.f ? v0 : v0 * a4.x;
        v1 = v1 > 0.f ? v1 : v1 * a4.y;
        v2 = v2 > 0.f ? v2 : v2 * a4.z;
        v3 = v3 > 0.f ? v3 : v3 * a4.w;
        if (lane < 32) {
            uint2 pk;
            pk.x = ((uint_t)f2bf(v1) << 16) | (uint_t)f2bf(v0);
            pk.y = ((uint_t)f2bf(v3) << 16) | (uint_t)f2bf(v2);
            uint2* outp = (uint2*)(isneg ? negb : posb);
            outp[(size_t)n * 16 + sub] = pk;
            if (!isneg) { s0 += v0; s1 += v1; s2 += v2; s3 += v3; }
        }
    }

    __shared__ float red[4][64];
    int w = tid >> 6;
    if (slot == 0) {
        red[w][sub * 4 + 0] = s0;
        red[w][sub * 4 + 1] = s1;
        red[w][sub * 4 + 2] = s2;
        red[w][sub * 4 + 3] = s3;
    }
    __syncthreads();
    if (tid < 64) {
        float s = red[0][tid] + red[1][tid] + red[2][tid] + red[3][tid];
        atomicAdd(&sumvec[tid], s);
    }
}

// ===== K5: loss (disc fused) + last-block final ============================
__global__ __launch_bounds__(256) void k_loss(const ushort_t* __restrict__ posb,
                                              const ushort_t* __restrict__ negb,
                                              float* __restrict__ smallb,
                                              const float* __restrict__ Wd,
                                              float* __restrict__ out, int N) {
    __shared__ float summ[64];
    __shared__ float svecS[64];
    __shared__ float redL[8];
    int tid = threadIdx.x;
    float* sumvec = smallb;
    float* lossAcc = smallb + 128;
    int* done = (int*)(smallb + 129);

    if (tid < 64) summ[tid] = 1.f / (1.f + expf(-sumvec[tid] / (float)N));
    __syncthreads();
    if (tid < 64) {
        float s = 0.f;
#pragma unroll
        for (int j = 0; j < 64; j++) s += Wd[tid * 64 + j] * summ[j];
        svecS[tid] = s;
    }
    __syncthreads();

    int lane = tid & 63;
    int half = lane >> 5;
    int sub = lane & 31;
    int w = tid >> 6;
    float s0 = svecS[2 * sub], s1 = svecS[2 * sub + 1];
    const uint_t* P32 = (const uint_t*)(half ? negb : posb);
    float l = 0.f;
    int wid = (blockIdx.x * 256 + tid) >> 6;
    int nw = gridDim.x * 4;
    for (int n = wid; n < N; n += nw) {
        uint_t u = P32[(size_t)n * 32 + sub];
        float p = lo_bf(u) * s0 + hi_bf(u) * s1;
        p += __shfl_xor(p, 1);
        p += __shfl_xor(p, 2);
        p += __shfl_xor(p, 4);
        p += __shfl_xor(p, 8);
        p += __shfl_xor(p, 16);
        if (sub == 0) l += half ? softplusf(p) : softplusf(-p);
    }
    if (sub == 0) redL[w * 2 + half] = l;
    __syncthreads();
    if (tid == 0) {
        float t = 0.f;
#pragma unroll
        for (int i = 0; i < 8; i++) t += redL[i];
        atomicAdd(&lossAcc[0], t);
        __threadfence();
        int old = atomicAdd(done, 1);
        if (old == (int)gridDim.x - 1) {
            float tot = atomicAdd(&lossAcc[0], 0.f);
            out[0] = tot / (float)N;
        }
    }
}

extern "C" void kernel_launch(void* const* d_in, const int* in_sizes, int n_in,
                              void* d_out, int out_size, void* d_ws, size_t ws_size,
                              hipStream_t stream) {
    const float* x      = (const float*)d_in[0];
    const float* W_gcn  = (const float*)d_in[1];
    const float* b_gcn  = (const float*)d_in[2];
    const float* prelu_a= (const float*)d_in[3];
    const float* W_disc = (const float*)d_in[4];
    const int*   eidx   = (const int*)d_in[5];
    const int*   perm   = (const int*)d_in[6];

    int N = in_sizes[0] / INDIM;      // 100000
    int E = in_sizes[5] / 2;          // 1600000
    const int* src = eidx;
    const int* dst = eidx + E;

    char* base = (char*)d_ws;
    size_t off = 0;
    auto alloc = [&](size_t bytes) { size_t o = off; off = (off + bytes + 255) & ~(size_t)255; return o; };
    uint_t*   Hq    = (uint_t*)  (base + alloc((size_t)N * HID));        // fp8: 6.4 MB
    ushort_t* posb  = (ushort_t*)(base + alloc((size_t)N * HID * 2));
    ushort_t* negb  = (ushort_t*)(base + alloc((size_t)N * HID * 2));
    int2*     csrS  = (int2*)   (base + alloc((size_t)E * 8));
    int2*     ebuf  = (int2*)   (base + alloc((size_t)NBUCK * EBUF_PER * 8));
    int*      rowptr= (int*)    (base + alloc(((size_t)N + 1) * 4));
    float*    dinv  = (float*)  (base + alloc((size_t)N * 4));
    // zero region: cnt[N] + bcur[NBUCK] + smallb[132] contiguous
    size_t zOff = alloc((size_t)N * 4 + NBUCK * 4 + 132 * 4);
    int*      cnt   = (int*)(base + zOff);
    int*      bcur  = (int*)(base + zOff + (size_t)N * 4);
    float*    smallb= (float*)(base + zOff + (size_t)N * 4 + NBUCK * 4);
    float* sumvec = smallb;

    int nbA = (E + CHUNK - 1) / CHUNK;    // 391
    int nbG = (N + 63) / 64;              // 1563
    int nbB = (N + 511) / 512;            // 196
    int nbN = (N + 255) / 256;

    hipMemsetAsync(cnt, 0, (size_t)N * 4 + NBUCK * 4 + 132 * 4, stream);
    k_fused<<<nbA + nbG, 256, 0, stream>>>(x, W_gcn, src, dst, Hq, cnt, bcur, ebuf, N, E, nbA);
    k_dinv<<<nbN, 256, 0, stream>>>(cnt, dinv, N);
    k_binB<<<nbB, 256, 0, stream>>>(ebuf, bcur, perm, dinv, csrS, rowptr, N, E);
    k_gather<<<2048, 256, 0, stream>>>(Hq, rowptr, csrS, perm, dinv,
                                       b_gcn, prelu_a, posb, negb, sumvec, N);
    k_loss<<<512, 256, 0, stream>>>(posb, negb, smallb, W_disc, (float*)d_out, N);
}

// Round 18
// 246.136 us; speedup vs baseline: 1.1152x; 1.1152x over previous
//
#include <hip/hip_runtime.h>

#define HID 64
#define INDIM 128
#define NBUCK 256          // bucket = dst >> 9  (512 nodes/bucket)
#define EBUF_PER 10240     // fixed ebuf region per bucket (avg fill 8192, 22 sigma)
#define CHUNK 4096         // edges per binA block

typedef unsigned short ushort_t;
typedef unsigned int uint_t;
typedef float floatx2 __attribute__((ext_vector_type(2)));

__device__ __forceinline__ float softplusf(float x) {
    return fmaxf(x, 0.f) + log1pf(expf(-fabsf(x)));
}
__device__ __forceinline__ ushort_t f2bf(float f) {
    union { float f; uint_t i; } c; c.f = f;
    uint_t u = c.i;
    u += 0x7FFFu + ((u >> 16) & 1u);
    return (ushort_t)(u >> 16);
}
__device__ __forceinline__ float lo_bf(uint_t u) {
    union { uint_t i; float f; } c; c.i = u << 16; return c.f;
}
__device__ __forceinline__ float hi_bf(uint_t u) {
    union { uint_t i; float f; } c; c.i = u & 0xFFFF0000u; return c.f;
}
__device__ __forceinline__ float dec_norm(uint_t x) {
    union { uint_t i; float f; } c; c.i = (x >> 17) << 16; return c.f;
}

// ===== K1: fused [binA (blocks 0..nbA) | gemm (rest)] ======================
// binA: LDS-binned bucket scatter into ebuf. NO global histogram (R15 form —
// degrees are derived per-bucket in binB1 from the ebuf runs).
// gemm: 64-row acc[4][4] (proven shape).
__global__ __launch_bounds__(256) void k_fused(const float* __restrict__ x,
                                               const float* __restrict__ W,
                                               const int* __restrict__ src,
                                               const int* __restrict__ dst,
                                               uint_t* __restrict__ Hq,
                                               int* __restrict__ bcur,
                                               int2* __restrict__ ebuf,
                                               int N, int E, int nbA) {
    __shared__ char lds[66560];
    int tid = threadIdx.x;

    if ((int)blockIdx.x < nbA) {
        // ---------------- binA ----------------
        int2* stage  = (int2*)lds;               // 32768
        int* lcnt    = (int*)(lds + 32768);
        int* binSt   = (int*)(lds + 33792);
        int* lofs    = (int*)(lds + 34816);
        int* gofs    = (int*)(lds + 35840);
        int* scn     = (int*)(lds + 36864);      // ..37888
        int base = blockIdx.x * CHUNK;

        lcnt[tid] = 0;
        __syncthreads();

        int sv[16], dv[16];
#pragma unroll
        for (int i = 0; i < 16; i++) {
            int e = base + i * 256 + tid;
            if (e < E) { sv[i] = src[e]; dv[i] = dst[e]; }
            else dv[i] = -1;
        }
#pragma unroll
        for (int i = 0; i < 16; i++)
            if (dv[i] >= 0) atomicAdd(&lcnt[dv[i] >> 9], 1);
        __syncthreads();

        scn[tid] = lcnt[tid];
        __syncthreads();
        for (int off = 1; off < NBUCK; off <<= 1) {
            int v = (tid >= off) ? scn[tid - off] : 0;
            __syncthreads();
            scn[tid] += v;
            __syncthreads();
        }
        binSt[tid] = scn[tid] - lcnt[tid];
        lofs[tid] = binSt[tid];
        __syncthreads();

#pragma unroll
        for (int i = 0; i < 16; i++) {
            if (dv[i] >= 0) {
                int b = dv[i] >> 9;
                int p = atomicAdd(&lofs[b], 1);
                stage[p] = make_int2(sv[i], dv[i]);
            }
        }
        __syncthreads();

        if (lcnt[tid] > 0)
            gofs[tid] = tid * EBUF_PER + atomicAdd(&bcur[tid], lcnt[tid]);
        __syncthreads();

        int total = (base + CHUNK <= E) ? CHUNK : (E > base ? E - base : 0);
        for (int idx = tid; idx < total; idx += 256) {
            int2 v = stage[idx];
            int b = v.y >> 9;
            ebuf[gofs[b] + (idx - binSt[b])] = v;
        }
    } else {
        // ---------------- gemm: 64 rows, acc[4][4] ----------------
        float* Xs = (float*)lds;                 // 64*132*4 = 33792
        float* Ws = (float*)(lds + 33792);       // 32768 -> total 66560
        int row0 = ((int)blockIdx.x - nbA) * 64;

        const float4* W4 = (const float4*)W;
        float4* Ws4 = (float4*)Ws;
#pragma unroll
        for (int i = 0; i < 8; i++) Ws4[tid + 256 * i] = W4[tid + 256 * i];

#pragma unroll
        for (int i = 0; i < 8; i++) {
            int j = tid + 256 * i;
            int r = j >> 5, c4 = j & 31;
            int row = row0 + r;
            float4 v = make_float4(0.f, 0.f, 0.f, 0.f);
            if (row < N) v = *(const float4*)(x + (size_t)row * INDIM + c4 * 4);
            *(float4*)(&Xs[r * 132 + c4 * 4]) = v;
        }
        __syncthreads();

        int tx = tid & 15;
        int ty = tid >> 4;
        float acc[4][4] = {};
        const float* xa = &Xs[(ty * 4) * 132];
#pragma unroll 4
        for (int k = 0; k < 128; k++) {
            float4 b = *(const float4*)(&Ws[k * 64 + tx * 4]);
#pragma unroll
            for (int i = 0; i < 4; i++) {
                float a = xa[i * 132 + k];
                acc[i][0] = fmaf(a, b.x, acc[i][0]);
                acc[i][1] = fmaf(a, b.y, acc[i][1]);
                acc[i][2] = fmaf(a, b.z, acc[i][2]);
                acc[i][3] = fmaf(a, b.w, acc[i][3]);
            }
        }
#pragma unroll
        for (int i = 0; i < 4; i++) {
            int row = row0 + ty * 4 + i;
            if (row < N) {
                uint_t u = 0;
                u = __builtin_amdgcn_cvt_pk_fp8_f32(acc[i][0], acc[i][1], u, false);
                u = __builtin_amdgcn_cvt_pk_fp8_f32(acc[i][2], acc[i][3], u, true);
                Hq[(size_t)row * 16 + tx] = u;
            }
        }
    }
}

// ===== K2: binB1 — per-bucket degrees -> rowptr, dinv (no global atomics) ==
__global__ __launch_bounds__(256) void k_binB1(const int2* __restrict__ ebuf,
                                               const int* __restrict__ bcur,
                                               int* __restrict__ rowptr,
                                               float* __restrict__ dinvg,
                                               int N, int E) {
    __shared__ int bb[NBUCK];
    __shared__ int sc[256];
    __shared__ int ldeg[512];
    int tid = threadIdx.x;
    int b = blockIdx.x;

    bb[tid] = bcur[tid];
    __syncthreads();
    for (int off = 1; off < NBUCK; off <<= 1) {
        int v = (tid >= off) ? bb[tid - off] : 0;
        __syncthreads();
        bb[tid] += v;
        __syncthreads();
    }
    int bucketBase = (b == 0) ? 0 : bb[b - 1];

    ldeg[tid] = 0;
    ldeg[tid + 256] = 0;
    __syncthreads();

    int start = b * EBUF_PER;
    int cb = bcur[b];
    for (int i = start + tid; i < start + cb; i += 256)
        atomicAdd(&ldeg[ebuf[i].y & 511], 1);
    __syncthreads();

    int d0 = ldeg[2 * tid], d1 = ldeg[2 * tid + 1];
    int s2 = d0 + d1;
    sc[tid] = s2;
    __syncthreads();
    for (int off = 1; off < 256; off <<= 1) {
        int v = (tid >= off) ? sc[tid - off] : 0;
        __syncthreads();
        sc[tid] += v;
        __syncthreads();
    }
    int ex = sc[tid] - s2;
    int n0 = (b << 9) + 2 * tid, n1 = n0 + 1;
    int r0 = bucketBase + ex, r1 = r0 + d0;
    if (n0 < N) { rowptr[n0] = r0; dinvg[n0] = rsqrtf((float)(d0 + 1)); }
    if (n1 < N) { rowptr[n1] = r1; dinvg[n1] = rsqrtf((float)(d1 + 1)); }
    if (b == 0 && tid == 0) rowptr[N] = E;
}

// ===== K3: binB2 — exact csr placement with packed norm ====================
// csrS[j] = { s | norm15<<17 , perm[s] }; norm15 = top 15 bits of f32 (sign=0)
__global__ __launch_bounds__(256) void k_binB2(const int2* __restrict__ ebuf,
                                               const int* __restrict__ bcur,
                                               const int* __restrict__ rowptr,
                                               const int* __restrict__ perm,
                                               const float* __restrict__ dinvg,
                                               int2* __restrict__ csrS, int N) {
    __shared__ int lcur[512];
    __shared__ float ldinv[512];
    int tid = threadIdx.x;
    int b = blockIdx.x;
    int nodeBase = b << 9;
    for (int i = tid; i < 512; i += 256) {
        int n = nodeBase + i;
        lcur[i] = (n < N) ? rowptr[n] : 0;
        ldinv[i] = (n < N) ? dinvg[n] : 0.f;
    }
    __syncthreads();

    int start = b * EBUF_PER;
    int cb = bcur[b];
    for (int i = start + tid; i < start + cb; i += 256) {
        int2 v = ebuf[i];
        int s = v.x, dl = v.y & 511;
        int j = atomicAdd(&lcur[dl], 1);
        float nm = dinvg[s] * ldinv[dl];
        union { float f; uint_t u; } cu; cu.f = nm;
        uint_t nb = (cu.u >> 16) & 0x7FFFu;
        csrS[j] = make_int2((int)((uint_t)s | (nb << 17)), perm[s]);
    }
}

// ===== K4: gather — fp8, slot layout, 3-stage pipeline, packed norms =======
// lane = (slot, sub16); slot = (pair, isneg). Each H load = 4 rows x 64 B.
__global__ __launch_bounds__(256) void k_gather(const uint_t* __restrict__ Hq,
                                                const int* __restrict__ rowptr,
                                                const int2* __restrict__ csrS,
                                                const int* __restrict__ perm,
                                                const float* __restrict__ dinv,
                                                const float* __restrict__ b,
                                                const float* __restrict__ a,
                                                ushort_t* __restrict__ posb,
                                                ushort_t* __restrict__ negb,
                                                float* __restrict__ sumvec, int N) {
    int tid = threadIdx.x;
    int lane = tid & 63;
    int slot = lane >> 4;
    int sub = lane & 15;
    int isneg = slot & 1;
    int pair = slot >> 1;
    int wid = (blockIdx.x * 256 + tid) >> 6;
    int nw = gridDim.x * 4;
    float4 b4 = ((const float4*)b)[sub];
    float4 a4 = ((const float4*)a)[sub];
    float s0 = 0.f, s1 = 0.f, s2 = 0.f, s3 = 0.f;

    for (int n = wid; n < N; n += nw) {
        float dv = dinv[n];
        float w2 = dv * dv;
        int beg = rowptr[n], end = rowptr[n + 1];
        float a0 = 0.f, a1 = 0.f, a2 = 0.f, a3 = 0.f;

        // ---- prologue: csr iter0 (cA) + iter1 (cB); H values iter0 (uc) ----
        int e0 = beg + pair, e1 = beg + 2 + pair, e2 = beg + 4 + pair, e3 = beg + 6 + pair;
        int2 cA0 = (e0 < end) ? csrS[e0] : make_int2(0, 0);
        int2 cA1 = (e1 < end) ? csrS[e1] : make_int2(0, 0);
        int2 cA2 = (e2 < end) ? csrS[e2] : make_int2(0, 0);
        int2 cA3 = (e3 < end) ? csrS[e3] : make_int2(0, 0);
        int f0 = e0 + 8, f1 = e1 + 8, f2 = e2 + 8, f3 = e3 + 8;
        int2 cB0 = (f0 < end) ? csrS[f0] : make_int2(0, 0);
        int2 cB1 = (f1 < end) ? csrS[f1] : make_int2(0, 0);
        int2 cB2 = (f2 < end) ? csrS[f2] : make_int2(0, 0);
        int2 cB3 = (f3 < end) ? csrS[f3] : make_int2(0, 0);
        uint_t uc0 = Hq[(size_t)(isneg ? (uint_t)cA0.y : ((uint_t)cA0.x & 0x1FFFFu)) * 16 + sub];
        uint_t uc1 = Hq[(size_t)(isneg ? (uint_t)cA1.y : ((uint_t)cA1.x & 0x1FFFFu)) * 16 + sub];
        uint_t uc2 = Hq[(size_t)(isneg ? (uint_t)cA2.y : ((uint_t)cA2.x & 0x1FFFFu)) * 16 + sub];
        uint_t uc3 = Hq[(size_t)(isneg ? (uint_t)cA3.y : ((uint_t)cA3.x & 0x1FFFFu)) * 16 + sub];

        for (int j = beg; j < end; j += 8) {
            // stage 1: csr two iters ahead
            int g0 = j + 16 + pair, g1 = j + 18 + pair, g2 = j + 20 + pair, g3 = j + 22 + pair;
            int2 cC0 = (g0 < end) ? csrS[g0] : make_int2(0, 0);
            int2 cC1 = (g1 < end) ? csrS[g1] : make_int2(0, 0);
            int2 cC2 = (g2 < end) ? csrS[g2] : make_int2(0, 0);
            int2 cC3 = (g3 < end) ? csrS[g3] : make_int2(0, 0);
            // stage 2: H loads one iter ahead (rows from cB)
            uint_t un0 = Hq[(size_t)(isneg ? (uint_t)cB0.y : ((uint_t)cB0.x & 0x1FFFFu)) * 16 + sub];
            uint_t un1 = Hq[(size_t)(isneg ? (uint_t)cB1.y : ((uint_t)cB1.x & 0x1FFFFu)) * 16 + sub];
            uint_t un2 = Hq[(size_t)(isneg ? (uint_t)cB2.y : ((uint_t)cB2.x & 0x1FFFFu)) * 16 + sub];
            uint_t un3 = Hq[(size_t)(isneg ? (uint_t)cB3.y : ((uint_t)cB3.x & 0x1FFFFu)) * 16 + sub];
            // stage 3: consume iter j (H in uc, norms decoded from cA)
            float mA0 = dec_norm((uint_t)cA0.x);
            float mA1 = dec_norm((uint_t)cA1.x);
            float mA2 = dec_norm((uint_t)cA2.x);
            float mA3 = dec_norm((uint_t)cA3.x);
            floatx2 lo, hi;
            lo = __builtin_amdgcn_cvt_pk_f32_fp8(uc0, false);
            hi = __builtin_amdgcn_cvt_pk_f32_fp8(uc0, true);
            a0 = fmaf(lo.x, mA0, a0); a1 = fmaf(lo.y, mA0, a1);
            a2 = fmaf(hi.x, mA0, a2); a3 = fmaf(hi.y, mA0, a3);
            lo = __builtin_amdgcn_cvt_pk_f32_fp8(uc1, false);
            hi = __builtin_amdgcn_cvt_pk_f32_fp8(uc1, true);
            a0 = fmaf(lo.x, mA1, a0); a1 = fmaf(lo.y, mA1, a1);
            a2 = fmaf(hi.x, mA1, a2); a3 = fmaf(hi.y, mA1, a3);
            lo = __builtin_amdgcn_cvt_pk_f32_fp8(uc2, false);
            hi = __builtin_amdgcn_cvt_pk_f32_fp8(uc2, true);
            a0 = fmaf(lo.x, mA2, a0); a1 = fmaf(lo.y, mA2, a1);
            a2 = fmaf(hi.x, mA2, a2); a3 = fmaf(hi.y, mA2, a3);
            lo = __builtin_amdgcn_cvt_pk_f32_fp8(uc3, false);
            hi = __builtin_amdgcn_cvt_pk_f32_fp8(uc3, true);
            a0 = fmaf(lo.x, mA3, a0); a1 = fmaf(lo.y, mA3, a1);
            a2 = fmaf(hi.x, mA3, a2); a3 = fmaf(hi.y, mA3, a3);
            // rotate
            cA0 = cB0; cA1 = cB1; cA2 = cB2; cA3 = cB3;
            cB0 = cC0; cB1 = cC1; cB2 = cC2; cB3 = cC3;
            uc0 = un0; uc1 = un1; uc2 = un2; uc3 = un3;
        }
        a0 += __shfl_xor(a0, 32);
        a1 += __shfl_xor(a1, 32);
        a2 += __shfl_xor(a2, 32);
        a3 += __shfl_xor(a3, 32);
        int selfrow = isneg ? perm[n] : n;
        uint_t us = Hq[(size_t)selfrow * 16 + sub];
        floatx2 slo = __builtin_amdgcn_cvt_pk_f32_fp8(us, false);
        floatx2 shi = __builtin_amdgcn_cvt_pk_f32_fp8(us, true);
        float v0 = fmaf(slo.x, w2, a0) + b4.x;
        float v1 = fmaf(slo.y, w2, a1) + b4.y;
        float v2 = fmaf(shi.x, w2, a2) + b4.z;
        float v3 = fmaf(shi.y, w2, a3) + b4.w;
        v0 = v0 > 0.f ? v0 : v0 * a4.x;
        v1 = v1 > 0.f ? v1 : v1 * a4.y;
        v2 = v2 > 0.f ? v2 : v2 * a4.z;
        v3 = v3 > 0.f ? v3 : v3 * a4.w;
        if (lane < 32) {
            uint2 pk;
            pk.x = ((uint_t)f2bf(v1) << 16) | (uint_t)f2bf(v0);
            pk.y = ((uint_t)f2bf(v3) << 16) | (uint_t)f2bf(v2);
            uint2* outp = (uint2*)(isneg ? negb : posb);
            outp[(size_t)n * 16 + sub] = pk;
            if (!isneg) { s0 += v0; s1 += v1; s2 += v2; s3 += v3; }
        }
    }

    __shared__ float red[4][64];
    int w = tid >> 6;
    if (slot == 0) {
        red[w][sub * 4 + 0] = s0;
        red[w][sub * 4 + 1] = s1;
        red[w][sub * 4 + 2] = s2;
        red[w][sub * 4 + 3] = s3;
    }
    __syncthreads();
    if (tid < 64) {
        float s = red[0][tid] + red[1][tid] + red[2][tid] + red[3][tid];
        atomicAdd(&sumvec[tid], s);
    }
}

// ===== K5: loss (disc fused) + last-block final ============================
__global__ __launch_bounds__(256) void k_loss(const ushort_t* __restrict__ posb,
                                              const ushort_t* __restrict__ negb,
                                              float* __restrict__ smallb,
                                              const float* __restrict__ Wd,
                                              float* __restrict__ out, int N) {
    __shared__ float summ[64];
    __shared__ float svecS[64];
    __shared__ float redL[8];
    int tid = threadIdx.x;
    float* sumvec = smallb;
    float* lossAcc = smallb + 128;
    int* done = (int*)(smallb + 129);

    if (tid < 64) summ[tid] = 1.f / (1.f + expf(-sumvec[tid] / (float)N));
    __syncthreads();
    if (tid < 64) {
        float s = 0.f;
#pragma unroll
        for (int j = 0; j < 64; j++) s += Wd[tid * 64 + j] * summ[j];
        svecS[tid] = s;
    }
    __syncthreads();

    int lane = tid & 63;
    int half = lane >> 5;
    int sub = lane & 31;
    int w = tid >> 6;
    float s0 = svecS[2 * sub], s1 = svecS[2 * sub + 1];
    const uint_t* P32 = (const uint_t*)(half ? negb : posb);
    float l = 0.f;
    int wid = (blockIdx.x * 256 + tid) >> 6;
    int nw = gridDim.x * 4;
    for (int n = wid; n < N; n += nw) {
        uint_t u = P32[(size_t)n * 32 + sub];
        float p = lo_bf(u) * s0 + hi_bf(u) * s1;
        p += __shfl_xor(p, 1);
        p += __shfl_xor(p, 2);
        p += __shfl_xor(p, 4);
        p += __shfl_xor(p, 8);
        p += __shfl_xor(p, 16);
        if (sub == 0) l += half ? softplusf(p) : softplusf(-p);
    }
    if (sub == 0) redL[w * 2 + half] = l;
    __syncthreads();
    if (tid == 0) {
        float t = 0.f;
#pragma unroll
        for (int i = 0; i < 8; i++) t += redL[i];
        atomicAdd(&lossAcc[0], t);
        __threadfence();
        int old = atomicAdd(done, 1);
        if (old == (int)gridDim.x - 1) {
            float tot = atomicAdd(&lossAcc[0], 0.f);
            out[0] = tot / (float)N;
        }
    }
}

extern "C" void kernel_launch(void* const* d_in, const int* in_sizes, int n_in,
                              void* d_out, int out_size, void* d_ws, size_t ws_size,
                              hipStream_t stream) {
    const float* x      = (const float*)d_in[0];
    const float* W_gcn  = (const float*)d_in[1];
    const float* b_gcn  = (const float*)d_in[2];
    const float* prelu_a= (const float*)d_in[3];
    const float* W_disc = (const float*)d_in[4];
    const int*   eidx   = (const int*)d_in[5];
    const int*   perm   = (const int*)d_in[6];

    int N = in_sizes[0] / INDIM;      // 100000
    int E = in_sizes[5] / 2;          // 1600000
    const int* src = eidx;
    const int* dst = eidx + E;

    char* base = (char*)d_ws;
    size_t off = 0;
    auto alloc = [&](size_t bytes) { size_t o = off; off = (off + bytes + 255) & ~(size_t)255; return o; };
    uint_t*   Hq    = (uint_t*)  (base + alloc((size_t)N * HID));        // fp8: 6.4 MB
    ushort_t* posb  = (ushort_t*)(base + alloc((size_t)N * HID * 2));
    ushort_t* negb  = (ushort_t*)(base + alloc((size_t)N * HID * 2));
    int2*     csrS  = (int2*)   (base + alloc((size_t)E * 8));
    int2*     ebuf  = (int2*)   (base + alloc((size_t)NBUCK * EBUF_PER * 8));
    int*      rowptr= (int*)    (base + alloc(((size_t)N + 1) * 4));
    float*    dinv  = (float*)  (base + alloc((size_t)N * 4));
    // zero region: bcur[NBUCK] + smallb[132] contiguous (tiny)
    size_t zOff = alloc(NBUCK * 4 + 132 * 4);
    int*      bcur  = (int*)(base + zOff);
    float*    smallb= (float*)(base + zOff + NBUCK * 4);
    float* sumvec = smallb;

    int nbA = (E + CHUNK - 1) / CHUNK;    // 391
    int nbG = (N + 63) / 64;              // 1563
    int nbB = (N + 511) / 512;            // 196

    hipMemsetAsync(bcur, 0, NBUCK * 4 + 132 * 4, stream);
    k_fused<<<nbA + nbG, 256, 0, stream>>>(x, W_gcn, src, dst, Hq, bcur, ebuf, N, E, nbA);
    k_binB1<<<nbB, 256, 0, stream>>>(ebuf, bcur, rowptr, dinv, N, E);
    k_binB2<<<nbB, 256, 0, stream>>>(ebuf, bcur, rowptr, perm, dinv, csrS, N);
    k_gather<<<2048, 256, 0, stream>>>(Hq, rowptr, csrS, perm, dinv,
                                       b_gcn, prelu_a, posb, negb, sumvec, N);
    k_loss<<<512, 256, 0, stream>>>(posb, negb, smallb, W_disc, (float*)d_out, N);
}

// Round 19
// 242.695 us; speedup vs baseline: 1.1310x; 1.0142x over previous
//
#include <hip/hip_runtime.h>

#define HID 64
#define INDIM 128
#define NBUCK 256          // bucket = dst >> 9  (512 nodes/bucket)
#define EBUF_PER 10240     // fixed ebuf region per bucket (raw, 22 sigma)
#define PAD_PER 14336      // fixed padded csr region per bucket (10240+4096)
#define CHUNK 4096         // edges per binA block
#define RMASK 0x1FFFFu     // row-index mask (fault-safety for unconsumed loads)

typedef unsigned short ushort_t;
typedef unsigned int uint_t;
typedef float floatx2 __attribute__((ext_vector_type(2)));

__device__ __forceinline__ float softplusf(float x) {
    return fmaxf(x, 0.f) + log1pf(expf(-fabsf(x)));
}
__device__ __forceinline__ ushort_t f2bf(float f) {
    union { float f; uint_t i; } c; c.f = f;
    uint_t u = c.i;
    u += 0x7FFFu + ((u >> 16) & 1u);
    return (ushort_t)(u >> 16);
}
__device__ __forceinline__ float lo_bf(uint_t u) {
    union { uint_t i; float f; } c; c.i = u << 16; return c.f;
}
__device__ __forceinline__ float hi_bf(uint_t u) {
    union { uint_t i; float f; } c; c.i = u & 0xFFFF0000u; return c.f;
}
__device__ __forceinline__ float dec_norm(uint_t x) {
    union { uint_t i; float f; } c; c.i = (x >> 17) << 16; return c.f;
}

// ===== K1: fused [binA (blocks 0..nbA) | gemm (rest)] ======================
__global__ __launch_bounds__(256) void k_fused(const float* __restrict__ x,
                                               const float* __restrict__ W,
                                               const int* __restrict__ src,
                                               const int* __restrict__ dst,
                                               uint_t* __restrict__ Hq,
                                               int* __restrict__ bcur,
                                               int2* __restrict__ ebuf,
                                               int N, int E, int nbA) {
    __shared__ char lds[66560];
    int tid = threadIdx.x;

    if ((int)blockIdx.x < nbA) {
        // ---------------- binA ----------------
        int2* stage  = (int2*)lds;               // 32768
        int* lcnt    = (int*)(lds + 32768);
        int* binSt   = (int*)(lds + 33792);
        int* lofs    = (int*)(lds + 34816);
        int* gofs    = (int*)(lds + 35840);
        int* scn     = (int*)(lds + 36864);      // ..37888
        int base = blockIdx.x * CHUNK;

        lcnt[tid] = 0;
        __syncthreads();

        int sv[16], dv[16];
#pragma unroll
        for (int i = 0; i < 16; i++) {
            int e = base + i * 256 + tid;
            if (e < E) { sv[i] = src[e]; dv[i] = dst[e]; }
            else dv[i] = -1;
        }
#pragma unroll
        for (int i = 0; i < 16; i++)
            if (dv[i] >= 0) atomicAdd(&lcnt[dv[i] >> 9], 1);
        __syncthreads();

        scn[tid] = lcnt[tid];
        __syncthreads();
        for (int off = 1; off < NBUCK; off <<= 1) {
            int v = (tid >= off) ? scn[tid - off] : 0;
            __syncthreads();
            scn[tid] += v;
            __syncthreads();
        }
        binSt[tid] = scn[tid] - lcnt[tid];
        lofs[tid] = binSt[tid];
        __syncthreads();

#pragma unroll
        for (int i = 0; i < 16; i++) {
            if (dv[i] >= 0) {
                int b = dv[i] >> 9;
                int p = atomicAdd(&lofs[b], 1);
                stage[p] = make_int2(sv[i], dv[i]);
            }
        }
        __syncthreads();

        if (lcnt[tid] > 0)
            gofs[tid] = tid * EBUF_PER + atomicAdd(&bcur[tid], lcnt[tid]);
        __syncthreads();

        int total = (base + CHUNK <= E) ? CHUNK : (E > base ? E - base : 0);
        for (int idx = tid; idx < total; idx += 256) {
            int2 v = stage[idx];
            int b = v.y >> 9;
            ebuf[gofs[b] + (idx - binSt[b])] = v;
        }
    } else {
        // ------- gemm: 64 rows, acc[4][4], float4 LDS reads (2 b128/k) -----
        float* Xs = (float*)lds;                 // 64*132*4 = 33792
        float* Ws = (float*)(lds + 33792);       // 32768 -> total 66560
        int row0 = ((int)blockIdx.x - nbA) * 64;

        const float4* W4 = (const float4*)W;
        float4* Ws4 = (float4*)Ws;
#pragma unroll
        for (int i = 0; i < 8; i++) Ws4[tid + 256 * i] = W4[tid + 256 * i];

#pragma unroll
        for (int i = 0; i < 8; i++) {
            int j = tid + 256 * i;
            int r = j >> 5, c4 = j & 31;
            int row = row0 + r;
            float4 v = make_float4(0.f, 0.f, 0.f, 0.f);
            if (row < N) v = *(const float4*)(x + (size_t)row * INDIM + c4 * 4);
            *(float4*)(&Xs[r * 132 + c4 * 4]) = v;
        }
        __syncthreads();

        int tx = tid & 15;
        int ty = tid >> 4;
        float acc[4][4] = {};
        const float* xa = &Xs[(ty * 4) * 132];
#pragma unroll 4
        for (int k4 = 0; k4 < 32; k4++) {
            float4 x0 = *(const float4*)(&xa[k4 * 4]);
            float4 x1 = *(const float4*)(&xa[132 + k4 * 4]);
            float4 x2 = *(const float4*)(&xa[264 + k4 * 4]);
            float4 x3 = *(const float4*)(&xa[396 + k4 * 4]);
#pragma unroll
            for (int kk = 0; kk < 4; kk++) {
                float4 bv = *(const float4*)(&Ws[(k4 * 4 + kk) * 64 + tx * 4]);
                float a0 = ((const float*)&x0)[kk];
                float a1 = ((const float*)&x1)[kk];
                float a2 = ((const float*)&x2)[kk];
                float a3 = ((const float*)&x3)[kk];
                acc[0][0] = fmaf(a0, bv.x, acc[0][0]);
                acc[0][1] = fmaf(a0, bv.y, acc[0][1]);
                acc[0][2] = fmaf(a0, bv.z, acc[0][2]);
                acc[0][3] = fmaf(a0, bv.w, acc[0][3]);
                acc[1][0] = fmaf(a1, bv.x, acc[1][0]);
                acc[1][1] = fmaf(a1, bv.y, acc[1][1]);
                acc[1][2] = fmaf(a1, bv.z, acc[1][2]);
                acc[1][3] = fmaf(a1, bv.w, acc[1][3]);
                acc[2][0] = fmaf(a2, bv.x, acc[2][0]);
                acc[2][1] = fmaf(a2, bv.y, acc[2][1]);
                acc[2][2] = fmaf(a2, bv.z, acc[2][2]);
                acc[2][3] = fmaf(a2, bv.w, acc[2][3]);
                acc[3][0] = fmaf(a3, bv.x, acc[3][0]);
                acc[3][1] = fmaf(a3, bv.y, acc[3][1]);
                acc[3][2] = fmaf(a3, bv.z, acc[3][2]);
                acc[3][3] = fmaf(a3, bv.w, acc[3][3]);
            }
        }
#pragma unroll
        for (int i = 0; i < 4; i++) {
            int row = row0 + ty * 4 + i;
            if (row < N) {
                uint_t u = 0;
                u = __builtin_amdgcn_cvt_pk_fp8_f32(acc[i][0], acc[i][1], u, false);
                u = __builtin_amdgcn_cvt_pk_fp8_f32(acc[i][2], acc[i][3], u, true);
                Hq[(size_t)row * 16 + tx] = u;
            }
        }
    }
}

// ===== K2: binB1 — per-bucket degrees -> packed padded rowptr, dinv ========
// rowptr[n] = prow | (iters << 23); prow in fixed bucket region b*PAD_PER.
__global__ __launch_bounds__(256) void k_binB1(const int2* __restrict__ ebuf,
                                               const int* __restrict__ bcur,
                                               int* __restrict__ rowptr,
                                               float* __restrict__ dinvg,
                                               int N) {
    __shared__ int sc[256];
    __shared__ int ldeg[512];
    int tid = threadIdx.x;
    int b = blockIdx.x;

    ldeg[tid] = 0;
    ldeg[tid + 256] = 0;
    __syncthreads();

    int start = b * EBUF_PER;
    int cb = bcur[b];
    for (int i = start + tid; i < start + cb; i += 256)
        atomicAdd(&ldeg[ebuf[i].y & 511], 1);
    __syncthreads();

    int d0 = ldeg[2 * tid], d1 = ldeg[2 * tid + 1];
    int p0 = (d0 + 7) & ~7, p1 = (d1 + 7) & ~7;
    int s2 = p0 + p1;
    sc[tid] = s2;
    __syncthreads();
    for (int off = 1; off < 256; off <<= 1) {
        int v = (tid >= off) ? sc[tid - off] : 0;
        __syncthreads();
        sc[tid] += v;
        __syncthreads();
    }
    int ex = sc[tid] - s2;
    int n0 = (b << 9) + 2 * tid, n1 = n0 + 1;
    int prow0 = b * PAD_PER + ex;
    int prow1 = prow0 + p0;
    if (n0 < N) { rowptr[n0] = prow0 | ((p0 >> 3) << 23); dinvg[n0] = rsqrtf((float)(d0 + 1)); }
    if (n1 < N) { rowptr[n1] = prow1 | ((p1 >> 3) << 23); dinvg[n1] = rsqrtf((float)(d1 + 1)); }
}

// ===== K3: binB2 — placement with packed norm + zero pad-fill ==============
// csrS[j] = { s | norm15<<17 , perm[s] }; pads = {0,0} (norm 0, row 0)
__global__ __launch_bounds__(256) void k_binB2(const int2* __restrict__ ebuf,
                                               const int* __restrict__ bcur,
                                               const int* __restrict__ rowptr,
                                               const int* __restrict__ perm,
                                               const float* __restrict__ dinvg,
                                               int2* __restrict__ csrS, int N) {
    __shared__ int lcur[512];
    __shared__ float ldinv[512];
    int tid = threadIdx.x;
    int b = blockIdx.x;
    int nodeBase = b << 9;
    for (int i = tid; i < 512; i += 256) {
        int n = nodeBase + i;
        lcur[i] = (n < N) ? (rowptr[n] & 0x7FFFFF) : 0;
        ldinv[i] = (n < N) ? dinvg[n] : 0.f;
    }
    __syncthreads();

    int start = b * EBUF_PER;
    int cb = bcur[b];
    for (int i = start + tid; i < start + cb; i += 256) {
        int2 v = ebuf[i];
        int s = v.x, dl = v.y & 511;
        int j = atomicAdd(&lcur[dl], 1);
        float nm = dinvg[s] * ldinv[dl];
        union { float f; uint_t u; } cu; cu.f = nm;
        uint_t nb = (cu.u >> 16) & 0x7FFFu;
        csrS[j] = make_int2((int)((uint_t)s | (nb << 17)), perm[s]);
    }
    __syncthreads();

    // zero-fill pad slots: lcur[i] (=prow+deg) .. prow+8*iters
    for (int i = tid; i < 512; i += 256) {
        int n = nodeBase + i;
        if (n < N) {
            uint_t r = (uint_t)rowptr[n];
            int e = (int)(r & 0x7FFFFF) + 8 * (int)(r >> 23);
            for (int j = lcur[i]; j < e; j++) csrS[j] = make_int2(0, 0);
        }
    }
}

// ===== K4: gather — fp8, slot layout, 3-stage pipeline, branchless =========
// lane = (slot, sub16); slot = (pair, isneg). Runs padded to multiples of 8.
__global__ __launch_bounds__(256) void k_gather(const uint_t* __restrict__ Hq,
                                                const int* __restrict__ rowptr,
                                                const int2* __restrict__ csrS,
                                                const int* __restrict__ perm,
                                                const float* __restrict__ dinv,
                                                const float* __restrict__ b,
                                                const float* __restrict__ a,
                                                ushort_t* __restrict__ posb,
                                                ushort_t* __restrict__ negb,
                                                float* __restrict__ sumvec, int N) {
    int tid = threadIdx.x;
    int lane = tid & 63;
    int slot = lane >> 4;
    int sub = lane & 15;
    int isneg = slot & 1;
    int pair = slot >> 1;
    int wid = (blockIdx.x * 256 + tid) >> 6;
    int nw = gridDim.x * 4;
    float4 b4 = ((const float4*)b)[sub];
    float4 a4 = ((const float4*)a)[sub];
    float s0 = 0.f, s1 = 0.f, s2 = 0.f, s3 = 0.f;

    for (int n = wid; n < N; n += nw) {
        float dv = dinv[n];
        float w2 = dv * dv;
        uint_t r = (uint_t)rowptr[n];
        int beg = (int)(r & 0x7FFFFF);
        int iters = (int)(r >> 23);
        float a0 = 0.f, a1 = 0.f, a2 = 0.f, a3 = 0.f;

        int base0 = beg + pair;
        // prologue: csr iter0 (cA) + iter1 (cB); H values iter0 (uc) — no guards
        int2 cA0 = csrS[base0];
        int2 cA1 = csrS[base0 + 2];
        int2 cA2 = csrS[base0 + 4];
        int2 cA3 = csrS[base0 + 6];
        int2 cB0 = csrS[base0 + 8];
        int2 cB1 = csrS[base0 + 10];
        int2 cB2 = csrS[base0 + 12];
        int2 cB3 = csrS[base0 + 14];
        uint_t uc0 = Hq[(size_t)((isneg ? (uint_t)cA0.y : (uint_t)cA0.x) & RMASK) * 16 + sub];
        uint_t uc1 = Hq[(size_t)((isneg ? (uint_t)cA1.y : (uint_t)cA1.x) & RMASK) * 16 + sub];
        uint_t uc2 = Hq[(size_t)((isneg ? (uint_t)cA2.y : (uint_t)cA2.x) & RMASK) * 16 + sub];
        uint_t uc3 = Hq[(size_t)((isneg ? (uint_t)cA3.y : (uint_t)cA3.x) & RMASK) * 16 + sub];

        for (int it = 0; it < iters; it++) {
            int gbase = base0 + (it + 2) * 8;
            int2 cC0 = csrS[gbase];
            int2 cC1 = csrS[gbase + 2];
            int2 cC2 = csrS[gbase + 4];
            int2 cC3 = csrS[gbase + 6];
            uint_t un0 = Hq[(size_t)((isneg ? (uint_t)cB0.y : (uint_t)cB0.x) & RMASK) * 16 + sub];
            uint_t un1 = Hq[(size_t)((isneg ? (uint_t)cB1.y : (uint_t)cB1.x) & RMASK) * 16 + sub];
            uint_t un2 = Hq[(size_t)((isneg ? (uint_t)cB2.y : (uint_t)cB2.x) & RMASK) * 16 + sub];
            uint_t un3 = Hq[(size_t)((isneg ? (uint_t)cB3.y : (uint_t)cB3.x) & RMASK) * 16 + sub];
            float mA0 = dec_norm((uint_t)cA0.x);
            float mA1 = dec_norm((uint_t)cA1.x);
            float mA2 = dec_norm((uint_t)cA2.x);
            float mA3 = dec_norm((uint_t)cA3.x);
            floatx2 lo, hi;
            lo = __builtin_amdgcn_cvt_pk_f32_fp8(uc0, false);
            hi = __builtin_amdgcn_cvt_pk_f32_fp8(uc0, true);
            a0 = fmaf(lo.x, mA0, a0); a1 = fmaf(lo.y, mA0, a1);
            a2 = fmaf(hi.x, mA0, a2); a3 = fmaf(hi.y, mA0, a3);
            lo = __builtin_amdgcn_cvt_pk_f32_fp8(uc1, false);
            hi = __builtin_amdgcn_cvt_pk_f32_fp8(uc1, true);
            a0 = fmaf(lo.x, mA1, a0); a1 = fmaf(lo.y, mA1, a1);
            a2 = fmaf(hi.x, mA1, a2); a3 = fmaf(hi.y, mA1, a3);
            lo = __builtin_amdgcn_cvt_pk_f32_fp8(uc2, false);
            hi = __builtin_amdgcn_cvt_pk_f32_fp8(uc2, true);
            a0 = fmaf(lo.x, mA2, a0); a1 = fmaf(lo.y, mA2, a1);
            a2 = fmaf(hi.x, mA2, a2); a3 = fmaf(hi.y, mA2, a3);
            lo = __builtin_amdgcn_cvt_pk_f32_fp8(uc3, false);
            hi = __builtin_amdgcn_cvt_pk_f32_fp8(uc3, true);
            a0 = fmaf(lo.x, mA3, a0); a1 = fmaf(lo.y, mA3, a1);
            a2 = fmaf(hi.x, mA3, a2); a3 = fmaf(hi.y, mA3, a3);
            cA0 = cB0; cA1 = cB1; cA2 = cB2; cA3 = cB3;
            cB0 = cC0; cB1 = cC1; cB2 = cC2; cB3 = cC3;
            uc0 = un0; uc1 = un1; uc2 = un2; uc3 = un3;
        }
        a0 += __shfl_xor(a0, 32);
        a1 += __shfl_xor(a1, 32);
        a2 += __shfl_xor(a2, 32);
        a3 += __shfl_xor(a3, 32);
        int selfrow = isneg ? perm[n] : n;
        uint_t us = Hq[(size_t)selfrow * 16 + sub];
        floatx2 slo = __builtin_amdgcn_cvt_pk_f32_fp8(us, false);
        floatx2 shi = __builtin_amdgcn_cvt_pk_f32_fp8(us, true);
        float v0 = fmaf(slo.x, w2, a0) + b4.x;
        float v1 = fmaf(slo.y, w2, a1) + b4.y;
        float v2 = fmaf(shi.x, w2, a2) + b4.z;
        float v3 = fmaf(shi.y, w2, a3) + b4.w;
        v0 = v0 > 0.f ? v0 : v0 * a4.x;
        v1 = v1 > 0.f ? v1 : v1 * a4.y;
        v2 = v2 > 0.f ? v2 : v2 * a4.z;
        v3 = v3 > 0.f ? v3 : v3 * a4.w;
        if (lane < 32) {
            uint2 pk;
            pk.x = ((uint_t)f2bf(v1) << 16) | (uint_t)f2bf(v0);
            pk.y = ((uint_t)f2bf(v3) << 16) | (uint_t)f2bf(v2);
            uint2* outp = (uint2*)(isneg ? negb : posb);
            outp[(size_t)n * 16 + sub] = pk;
            if (!isneg) { s0 += v0; s1 += v1; s2 += v2; s3 += v3; }
        }
    }

    __shared__ float red[4][64];
    int w = tid >> 6;
    if (slot == 0) {
        red[w][sub * 4 + 0] = s0;
        red[w][sub * 4 + 1] = s1;
        red[w][sub * 4 + 2] = s2;
        red[w][sub * 4 + 3] = s3;
    }
    __syncthreads();
    if (tid < 64) {
        float s = red[0][tid] + red[1][tid] + red[2][tid] + red[3][tid];
        atomicAdd(&sumvec[tid], s);
    }
}

// ===== K5: loss (disc fused) + last-block final ============================
__global__ __launch_bounds__(256) void k_loss(const ushort_t* __restrict__ posb,
                                              const ushort_t* __restrict__ negb,
                                              float* __restrict__ smallb,
                                              const float* __restrict__ Wd,
                                              float* __restrict__ out, int N) {
    __shared__ float summ[64];
    __shared__ float svecS[64];
    __shared__ float redL[8];
    int tid = threadIdx.x;
    float* sumvec = smallb;
    float* lossAcc = smallb + 128;
    int* done = (int*)(smallb + 129);

    if (tid < 64) summ[tid] = 1.f / (1.f + expf(-sumvec[tid] / (float)N));
    __syncthreads();
    if (tid < 64) {
        float s = 0.f;
#pragma unroll
        for (int j = 0; j < 64; j++) s += Wd[tid * 64 + j] * summ[j];
        svecS[tid] = s;
    }
    __syncthreads();

    int lane = tid & 63;
    int half = lane >> 5;
    int sub = lane & 31;
    int w = tid >> 6;
    float s0 = svecS[2 * sub], s1 = svecS[2 * sub + 1];
    const uint_t* P32 = (const uint_t*)(half ? negb : posb);
    float l = 0.f;
    int wid = (blockIdx.x * 256 + tid) >> 6;
    int nw = gridDim.x * 4;
    for (int n = wid; n < N; n += nw) {
        uint_t u = P32[(size_t)n * 32 + sub];
        float p = lo_bf(u) * s0 + hi_bf(u) * s1;
        p += __shfl_xor(p, 1);
        p += __shfl_xor(p, 2);
        p += __shfl_xor(p, 4);
        p += __shfl_xor(p, 8);
        p += __shfl_xor(p, 16);
        if (sub == 0) l += half ? softplusf(p) : softplusf(-p);
    }
    if (sub == 0) redL[w * 2 + half] = l;
    __syncthreads();
    if (tid == 0) {
        float t = 0.f;
#pragma unroll
        for (int i = 0; i < 8; i++) t += redL[i];
        atomicAdd(&lossAcc[0], t);
        __threadfence();
        int old = atomicAdd(done, 1);
        if (old == (int)gridDim.x - 1) {
            float tot = atomicAdd(&lossAcc[0], 0.f);
            out[0] = tot / (float)N;
        }
    }
}

extern "C" void kernel_launch(void* const* d_in, const int* in_sizes, int n_in,
                              void* d_out, int out_size, void* d_ws, size_t ws_size,
                              hipStream_t stream) {
    const float* x      = (const float*)d_in[0];
    const float* W_gcn  = (const float*)d_in[1];
    const float* b_gcn  = (const float*)d_in[2];
    const float* prelu_a= (const float*)d_in[3];
    const float* W_disc = (const float*)d_in[4];
    const int*   eidx   = (const int*)d_in[5];
    const int*   perm   = (const int*)d_in[6];

    int N = in_sizes[0] / INDIM;      // 100000
    int E = in_sizes[5] / 2;          // 1600000
    const int* src = eidx;
    const int* dst = eidx + E;

    char* base = (char*)d_ws;
    size_t off = 0;
    auto alloc = [&](size_t bytes) { size_t o = off; off = (off + bytes + 255) & ~(size_t)255; return o; };
    uint_t*   Hq    = (uint_t*)  (base + alloc((size_t)N * HID));          // fp8: 6.4 MB
    ushort_t* posb  = (ushort_t*)(base + alloc((size_t)N * HID * 2));
    ushort_t* negb  = (ushort_t*)(base + alloc((size_t)N * HID * 2));
    int2*     csrS  = (int2*)   (base + alloc(((size_t)NBUCK * PAD_PER + 64) * 8));
    int2*     ebuf  = (int2*)   (base + alloc((size_t)NBUCK * EBUF_PER * 8));
    int*      rowptr= (int*)    (base + alloc(((size_t)N + 1) * 4));
    float*    dinv  = (float*)  (base + alloc((size_t)N * 4));
    size_t zOff = alloc(NBUCK * 4 + 132 * 4);
    int*      bcur  = (int*)(base + zOff);
    float*    smallb= (float*)(base + zOff + NBUCK * 4);
    float* sumvec = smallb;

    int nbA = (E + CHUNK - 1) / CHUNK;    // 391
    int nbG = (N + 63) / 64;              // 1563
    int nbB = (N + 511) / 512;            // 196

    hipMemsetAsync(bcur, 0, NBUCK * 4 + 132 * 4, stream);
    k_fused<<<nbA + nbG, 256, 0, stream>>>(x, W_gcn, src, dst, Hq, bcur, ebuf, N, E, nbA);
    k_binB1<<<nbB, 256, 0, stream>>>(ebuf, bcur, rowptr, dinv, N);
    k_binB2<<<nbB, 256, 0, stream>>>(ebuf, bcur, rowptr, perm, dinv, csrS, N);
    k_gather<<<2048, 256, 0, stream>>>(Hq, rowptr, csrS, perm, dinv,
                                       b_gcn, prelu_a, posb, negb, sumvec, N);
    k_loss<<<512, 256, 0, stream>>>(posb, negb, smallb, W_disc, (float*)d_out, N);
}

// Round 20
// 226.298 us; speedup vs baseline: 1.2130x; 1.0725x over previous
//
#include <hip/hip_runtime.h>

#define HID 64
#define INDIM 128
#define NBUCK 256          // bucket = dst >> 9  (512 nodes/bucket)
#define EBUF_PER 10240     // fixed ebuf region per bucket (raw, 22 sigma)
#define PAD_PER 14336      // fixed padded csr region per bucket
#define CHUNK 4096         // edges per binA block
#define RMASK 0x1FFFFu     // row-index mask (fault-safety for unconsumed loads)

typedef unsigned short ushort_t;
typedef unsigned int uint_t;
typedef float floatx2 __attribute__((ext_vector_type(2)));

__device__ __forceinline__ float softplusf(float x) {
    return fmaxf(x, 0.f) + log1pf(expf(-fabsf(x)));
}
__device__ __forceinline__ float dec_norm(uint_t x) {
    union { uint_t i; float f; } c; c.i = (x >> 17) << 16; return c.f;
}

// ===== K1: fused [binA (blocks 0..nbA) | gemm (rest)] ======================
__global__ __launch_bounds__(256) void k_fused(const float* __restrict__ x,
                                               const float* __restrict__ W,
                                               const int* __restrict__ src,
                                               const int* __restrict__ dst,
                                               uint_t* __restrict__ Hq,
                                               int* __restrict__ bcur,
                                               int2* __restrict__ ebuf,
                                               int N, int E, int nbA) {
    __shared__ char lds[66560];
    int tid = threadIdx.x;

    if ((int)blockIdx.x < nbA) {
        // ---------------- binA ----------------
        int2* stage  = (int2*)lds;               // 32768
        int* lcnt    = (int*)(lds + 32768);
        int* binSt   = (int*)(lds + 33792);
        int* lofs    = (int*)(lds + 34816);
        int* gofs    = (int*)(lds + 35840);
        int* scn     = (int*)(lds + 36864);      // ..37888
        int base = blockIdx.x * CHUNK;

        lcnt[tid] = 0;
        __syncthreads();

        int sv[16], dv[16];
#pragma unroll
        for (int i = 0; i < 16; i++) {
            int e = base + i * 256 + tid;
            if (e < E) { sv[i] = src[e]; dv[i] = dst[e]; }
            else dv[i] = -1;
        }
#pragma unroll
        for (int i = 0; i < 16; i++)
            if (dv[i] >= 0) atomicAdd(&lcnt[dv[i] >> 9], 1);
        __syncthreads();

        scn[tid] = lcnt[tid];
        __syncthreads();
        for (int off = 1; off < NBUCK; off <<= 1) {
            int v = (tid >= off) ? scn[tid - off] : 0;
            __syncthreads();
            scn[tid] += v;
            __syncthreads();
        }
        binSt[tid] = scn[tid] - lcnt[tid];
        lofs[tid] = binSt[tid];
        __syncthreads();

#pragma unroll
        for (int i = 0; i < 16; i++) {
            if (dv[i] >= 0) {
                int b = dv[i] >> 9;
                int p = atomicAdd(&lofs[b], 1);
                stage[p] = make_int2(sv[i], dv[i]);
            }
        }
        __syncthreads();

        if (lcnt[tid] > 0)
            gofs[tid] = tid * EBUF_PER + atomicAdd(&bcur[tid], lcnt[tid]);
        __syncthreads();

        int total = (base + CHUNK <= E) ? CHUNK : (E > base ? E - base : 0);
        for (int idx = tid; idx < total; idx += 256) {
            int2 v = stage[idx];
            int b = v.y >> 9;
            ebuf[gofs[b] + (idx - binSt[b])] = v;
        }
    } else {
        // ------- gemm: 64 rows, acc[4][4], float4 LDS reads ----------------
        float* Xs = (float*)lds;                 // 64*132*4 = 33792
        float* Ws = (float*)(lds + 33792);       // 32768 -> total 66560
        int row0 = ((int)blockIdx.x - nbA) * 64;

        const float4* W4 = (const float4*)W;
        float4* Ws4 = (float4*)Ws;
#pragma unroll
        for (int i = 0; i < 8; i++) Ws4[tid + 256 * i] = W4[tid + 256 * i];

#pragma unroll
        for (int i = 0; i < 8; i++) {
            int j = tid + 256 * i;
            int r = j >> 5, c4 = j & 31;
            int row = row0 + r;
            float4 v = make_float4(0.f, 0.f, 0.f, 0.f);
            if (row < N) v = *(const float4*)(x + (size_t)row * INDIM + c4 * 4);
            *(float4*)(&Xs[r * 132 + c4 * 4]) = v;
        }
        __syncthreads();

        int tx = tid & 15;
        int ty = tid >> 4;
        float acc[4][4] = {};
        const float* xa = &Xs[(ty * 4) * 132];
#pragma unroll 4
        for (int k4 = 0; k4 < 32; k4++) {
            float4 x0 = *(const float4*)(&xa[k4 * 4]);
            float4 x1 = *(const float4*)(&xa[132 + k4 * 4]);
            float4 x2 = *(const float4*)(&xa[264 + k4 * 4]);
            float4 x3 = *(const float4*)(&xa[396 + k4 * 4]);
#pragma unroll
            for (int kk = 0; kk < 4; kk++) {
                float4 bv = *(const float4*)(&Ws[(k4 * 4 + kk) * 64 + tx * 4]);
                float a0 = ((const float*)&x0)[kk];
                float a1 = ((const float*)&x1)[kk];
                float a2 = ((const float*)&x2)[kk];
                float a3 = ((const float*)&x3)[kk];
                acc[0][0] = fmaf(a0, bv.x, acc[0][0]);
                acc[0][1] = fmaf(a0, bv.y, acc[0][1]);
                acc[0][2] = fmaf(a0, bv.z, acc[0][2]);
                acc[0][3] = fmaf(a0, bv.w, acc[0][3]);
                acc[1][0] = fmaf(a1, bv.x, acc[1][0]);
                acc[1][1] = fmaf(a1, bv.y, acc[1][1]);
                acc[1][2] = fmaf(a1, bv.z, acc[1][2]);
                acc[1][3] = fmaf(a1, bv.w, acc[1][3]);
                acc[2][0] = fmaf(a2, bv.x, acc[2][0]);
                acc[2][1] = fmaf(a2, bv.y, acc[2][1]);
                acc[2][2] = fmaf(a2, bv.z, acc[2][2]);
                acc[2][3] = fmaf(a2, bv.w, acc[2][3]);
                acc[3][0] = fmaf(a3, bv.x, acc[3][0]);
                acc[3][1] = fmaf(a3, bv.y, acc[3][1]);
                acc[3][2] = fmaf(a3, bv.z, acc[3][2]);
                acc[3][3] = fmaf(a3, bv.w, acc[3][3]);
            }
        }
#pragma unroll
        for (int i = 0; i < 4; i++) {
            int row = row0 + ty * 4 + i;
            if (row < N) {
                uint_t u = 0;
                u = __builtin_amdgcn_cvt_pk_fp8_f32(acc[i][0], acc[i][1], u, false);
                u = __builtin_amdgcn_cvt_pk_fp8_f32(acc[i][2], acc[i][3], u, true);
                Hq[(size_t)row * 16 + tx] = u;
            }
        }
    }
}

// ===== K2: binB1 — per-bucket degrees -> packed padded rowptr, dinv ========
__global__ __launch_bounds__(256) void k_binB1(const int2* __restrict__ ebuf,
                                               const int* __restrict__ bcur,
                                               int* __restrict__ rowptr,
                                               float* __restrict__ dinvg,
                                               int N) {
    __shared__ int sc[256];
    __shared__ int ldeg[512];
    int tid = threadIdx.x;
    int b = blockIdx.x;

    ldeg[tid] = 0;
    ldeg[tid + 256] = 0;
    __syncthreads();

    int start = b * EBUF_PER;
    int cb = bcur[b];
    for (int i = start + tid; i < start + cb; i += 256)
        atomicAdd(&ldeg[ebuf[i].y & 511], 1);
    __syncthreads();

    int d0 = ldeg[2 * tid], d1 = ldeg[2 * tid + 1];
    int p0 = (d0 + 7) & ~7, p1 = (d1 + 7) & ~7;
    int s2 = p0 + p1;
    sc[tid] = s2;
    __syncthreads();
    for (int off = 1; off < 256; off <<= 1) {
        int v = (tid >= off) ? sc[tid - off] : 0;
        __syncthreads();
        sc[tid] += v;
        __syncthreads();
    }
    int ex = sc[tid] - s2;
    int n0 = (b << 9) + 2 * tid, n1 = n0 + 1;
    int prow0 = b * PAD_PER + ex;
    int prow1 = prow0 + p0;
    if (n0 < N) { rowptr[n0] = prow0 | ((p0 >> 3) << 23); dinvg[n0] = rsqrtf((float)(d0 + 1)); }
    if (n1 < N) { rowptr[n1] = prow1 | ((p1 >> 3) << 23); dinvg[n1] = rsqrtf((float)(d1 + 1)); }
}

// ===== K3: binB2 — placement with packed norm + zero pad-fill ==============
__global__ __launch_bounds__(256) void k_binB2(const int2* __restrict__ ebuf,
                                               const int* __restrict__ bcur,
                                               const int* __restrict__ rowptr,
                                               const int* __restrict__ perm,
                                               const float* __restrict__ dinvg,
                                               int2* __restrict__ csrS, int N) {
    __shared__ int lcur[512];
    __shared__ float ldinv[512];
    int tid = threadIdx.x;
    int b = blockIdx.x;
    int nodeBase = b << 9;
    for (int i = tid; i < 512; i += 256) {
        int n = nodeBase + i;
        lcur[i] = (n < N) ? (rowptr[n] & 0x7FFFFF) : 0;
        ldinv[i] = (n < N) ? dinvg[n] : 0.f;
    }
    __syncthreads();

    int start = b * EBUF_PER;
    int cb = bcur[b];
    for (int i = start + tid; i < start + cb; i += 256) {
        int2 v = ebuf[i];
        int s = v.x, dl = v.y & 511;
        int j = atomicAdd(&lcur[dl], 1);
        float nm = dinvg[s] * ldinv[dl];
        union { float f; uint_t u; } cu; cu.f = nm;
        uint_t nb = (cu.u >> 16) & 0x7FFFu;
        csrS[j] = make_int2((int)((uint_t)s | (nb << 17)), perm[s]);
    }
    __syncthreads();

    for (int i = tid; i < 512; i += 256) {
        int n = nodeBase + i;
        if (n < N) {
            uint_t r = (uint_t)rowptr[n];
            int e = (int)(r & 0x7FFFFF) + 8 * (int)(r >> 23);
            for (int j = lcur[i]; j < e; j++) csrS[j] = make_int2(0, 0);
        }
    }
}

// ===== K4: gather — fp8 in, fp8 out; branchless 3-stage pipeline ===========
__global__ __launch_bounds__(256) void k_gather(const uint_t* __restrict__ Hq,
                                                const int* __restrict__ rowptr,
                                                const int2* __restrict__ csrS,
                                                const int* __restrict__ perm,
                                                const float* __restrict__ dinv,
                                                const float* __restrict__ b,
                                                const float* __restrict__ a,
                                                uint_t* __restrict__ posq,
                                                uint_t* __restrict__ negq,
                                                float* __restrict__ sumvec, int N) {
    int tid = threadIdx.x;
    int lane = tid & 63;
    int slot = lane >> 4;
    int sub = lane & 15;
    int isneg = slot & 1;
    int pair = slot >> 1;
    int wid = (blockIdx.x * 256 + tid) >> 6;
    int nw = gridDim.x * 4;
    float4 b4 = ((const float4*)b)[sub];
    float4 a4 = ((const float4*)a)[sub];
    float s0 = 0.f, s1 = 0.f, s2 = 0.f, s3 = 0.f;

    for (int n = wid; n < N; n += nw) {
        float dv = dinv[n];
        float w2 = dv * dv;
        uint_t r = (uint_t)rowptr[n];
        int beg = (int)(r & 0x7FFFFF);
        int iters = (int)(r >> 23);
        float a0 = 0.f, a1 = 0.f, a2 = 0.f, a3 = 0.f;

        int base0 = beg + pair;
        int2 cA0 = csrS[base0];
        int2 cA1 = csrS[base0 + 2];
        int2 cA2 = csrS[base0 + 4];
        int2 cA3 = csrS[base0 + 6];
        int2 cB0 = csrS[base0 + 8];
        int2 cB1 = csrS[base0 + 10];
        int2 cB2 = csrS[base0 + 12];
        int2 cB3 = csrS[base0 + 14];
        uint_t uc0 = Hq[(size_t)((isneg ? (uint_t)cA0.y : (uint_t)cA0.x) & RMASK) * 16 + sub];
        uint_t uc1 = Hq[(size_t)((isneg ? (uint_t)cA1.y : (uint_t)cA1.x) & RMASK) * 16 + sub];
        uint_t uc2 = Hq[(size_t)((isneg ? (uint_t)cA2.y : (uint_t)cA2.x) & RMASK) * 16 + sub];
        uint_t uc3 = Hq[(size_t)((isneg ? (uint_t)cA3.y : (uint_t)cA3.x) & RMASK) * 16 + sub];

        for (int it = 0; it < iters; it++) {
            int gbase = base0 + (it + 2) * 8;
            int2 cC0 = csrS[gbase];
            int2 cC1 = csrS[gbase + 2];
            int2 cC2 = csrS[gbase + 4];
            int2 cC3 = csrS[gbase + 6];
            uint_t un0 = Hq[(size_t)((isneg ? (uint_t)cB0.y : (uint_t)cB0.x) & RMASK) * 16 + sub];
            uint_t un1 = Hq[(size_t)((isneg ? (uint_t)cB1.y : (uint_t)cB1.x) & RMASK) * 16 + sub];
            uint_t un2 = Hq[(size_t)((isneg ? (uint_t)cB2.y : (uint_t)cB2.x) & RMASK) * 16 + sub];
            uint_t un3 = Hq[(size_t)((isneg ? (uint_t)cB3.y : (uint_t)cB3.x) & RMASK) * 16 + sub];
            float mA0 = dec_norm((uint_t)cA0.x);
            float mA1 = dec_norm((uint_t)cA1.x);
            float mA2 = dec_norm((uint_t)cA2.x);
            float mA3 = dec_norm((uint_t)cA3.x);
            floatx2 lo, hi;
            lo = __builtin_amdgcn_cvt_pk_f32_fp8(uc0, false);
            hi = __builtin_amdgcn_cvt_pk_f32_fp8(uc0, true);
            a0 = fmaf(lo.x, mA0, a0); a1 = fmaf(lo.y, mA0, a1);
            a2 = fmaf(hi.x, mA0, a2); a3 = fmaf(hi.y, mA0, a3);
            lo = __builtin_amdgcn_cvt_pk_f32_fp8(uc1, false);
            hi = __builtin_amdgcn_cvt_pk_f32_fp8(uc1, true);
            a0 = fmaf(lo.x, mA1, a0); a1 = fmaf(lo.y, mA1, a1);
            a2 = fmaf(hi.x, mA1, a2); a3 = fmaf(hi.y, mA1, a3);
            lo = __builtin_amdgcn_cvt_pk_f32_fp8(uc2, false);
            hi = __builtin_amdgcn_cvt_pk_f32_fp8(uc2, true);
            a0 = fmaf(lo.x, mA2, a0); a1 = fmaf(lo.y, mA2, a1);
            a2 = fmaf(hi.x, mA2, a2); a3 = fmaf(hi.y, mA2, a3);
            lo = __builtin_amdgcn_cvt_pk_f32_fp8(uc3, false);
            hi = __builtin_amdgcn_cvt_pk_f32_fp8(uc3, true);
            a0 = fmaf(lo.x, mA3, a0); a1 = fmaf(lo.y, mA3, a1);
            a2 = fmaf(hi.x, mA3, a2); a3 = fmaf(hi.y, mA3, a3);
            cA0 = cB0; cA1 = cB1; cA2 = cB2; cA3 = cB3;
            cB0 = cC0; cB1 = cC1; cB2 = cC2; cB3 = cC3;
            uc0 = un0; uc1 = un1; uc2 = un2; uc3 = un3;
        }
        a0 += __shfl_xor(a0, 32);
        a1 += __shfl_xor(a1, 32);
        a2 += __shfl_xor(a2, 32);
        a3 += __shfl_xor(a3, 32);
        int selfrow = isneg ? perm[n] : n;
        uint_t us = Hq[(size_t)selfrow * 16 + sub];
        floatx2 slo = __builtin_amdgcn_cvt_pk_f32_fp8(us, false);
        floatx2 shi = __builtin_amdgcn_cvt_pk_f32_fp8(us, true);
        float v0 = fmaf(slo.x, w2, a0) + b4.x;
        float v1 = fmaf(slo.y, w2, a1) + b4.y;
        float v2 = fmaf(shi.x, w2, a2) + b4.z;
        float v3 = fmaf(shi.y, w2, a3) + b4.w;
        v0 = v0 > 0.f ? v0 : v0 * a4.x;
        v1 = v1 > 0.f ? v1 : v1 * a4.y;
        v2 = v2 > 0.f ? v2 : v2 * a4.z;
        v3 = v3 > 0.f ? v3 : v3 * a4.w;
        if (lane < 32) {
            uint_t pk = 0;
            pk = __builtin_amdgcn_cvt_pk_fp8_f32(v0, v1, pk, false);
            pk = __builtin_amdgcn_cvt_pk_fp8_f32(v2, v3, pk, true);
            uint_t* outp = isneg ? negq : posq;
            outp[(size_t)n * 16 + sub] = pk;
            if (!isneg) { s0 += v0; s1 += v1; s2 += v2; s3 += v3; }
        }
    }

    __shared__ float red[4][64];
    int w = tid >> 6;
    if (slot == 0) {
        red[w][sub * 4 + 0] = s0;
        red[w][sub * 4 + 1] = s1;
        red[w][sub * 4 + 2] = s2;
        red[w][sub * 4 + 3] = s3;
    }
    __syncthreads();
    if (tid < 64) {
        float s = red[0][tid] + red[1][tid] + red[2][tid] + red[3][tid];
        atomicAdd(&sumvec[tid], s);
    }
}

// ===== K5: loss — fp8 pos/neg, 2 nodes/wave-iter, disc fused, final ========
__global__ __launch_bounds__(256) void k_loss(const uint_t* __restrict__ posq,
                                              const uint_t* __restrict__ negq,
                                              float* __restrict__ smallb,
                                              const float* __restrict__ Wd,
                                              float* __restrict__ out, int N) {
    __shared__ float summ[64];
    __shared__ float svecS[64];
    __shared__ float redL[4][4];
    int tid = threadIdx.x;
    float* sumvec = smallb;
    float* lossAcc = smallb + 128;
    int* done = (int*)(smallb + 129);

    if (tid < 64) summ[tid] = 1.f / (1.f + expf(-sumvec[tid] / (float)N));
    __syncthreads();
    if (tid < 64) {
        float s = 0.f;
#pragma unroll
        for (int j = 0; j < 64; j++) s += Wd[tid * 64 + j] * summ[j];
        svecS[tid] = s;
    }
    __syncthreads();

    int lane = tid & 63;
    int slot = lane >> 4;
    int sub = lane & 15;
    int isneg = slot & 1;
    int pair = slot >> 1;
    int w = tid >> 6;
    float4 sv = ((const float4*)svecS)[sub];
    const uint_t* Pb = isneg ? negq : posq;
    float l = 0.f;
    int wid = (blockIdx.x * 256 + tid) >> 6;
    int nw = gridDim.x * 4;
    for (int g = wid; 2 * g < N; g += nw) {
        int row = 2 * g + pair;
        bool valid = row < N;
        uint_t u = valid ? Pb[(size_t)row * 16 + sub] : 0u;
        floatx2 lo = __builtin_amdgcn_cvt_pk_f32_fp8(u, false);
        floatx2 hi = __builtin_amdgcn_cvt_pk_f32_fp8(u, true);
        float p = lo.x * sv.x + lo.y * sv.y + hi.x * sv.z + hi.y * sv.w;
        p += __shfl_xor(p, 1);
        p += __shfl_xor(p, 2);
        p += __shfl_xor(p, 4);
        p += __shfl_xor(p, 8);
        if (sub == 0 && valid) l += isneg ? softplusf(p) : softplusf(-p);
    }
    if (sub == 0) redL[w][slot] = l;
    __syncthreads();
    if (tid == 0) {
        float t = 0.f;
#pragma unroll
        for (int i = 0; i < 4; i++)
#pragma unroll
            for (int j = 0; j < 4; j++) t += redL[i][j];
        atomicAdd(&lossAcc[0], t);
        __threadfence();
        int old = atomicAdd(done, 1);
        if (old == (int)gridDim.x - 1) {
            float tot = atomicAdd(&lossAcc[0], 0.f);
            out[0] = tot / (float)N;
        }
    }
}

extern "C" void kernel_launch(void* const* d_in, const int* in_sizes, int n_in,
                              void* d_out, int out_size, void* d_ws, size_t ws_size,
                              hipStream_t stream) {
    const float* x      = (const float*)d_in[0];
    const float* W_gcn  = (const float*)d_in[1];
    const float* b_gcn  = (const float*)d_in[2];
    const float* prelu_a= (const float*)d_in[3];
    const float* W_disc = (const float*)d_in[4];
    const int*   eidx   = (const int*)d_in[5];
    const int*   perm   = (const int*)d_in[6];

    int N = in_sizes[0] / INDIM;      // 100000
    int E = in_sizes[5] / 2;          // 1600000
    const int* src = eidx;
    const int* dst = eidx + E;

    char* base = (char*)d_ws;
    size_t off = 0;
    auto alloc = [&](size_t bytes) { size_t o = off; off = (off + bytes + 255) & ~(size_t)255; return o; };
    uint_t*   Hq    = (uint_t*)  (base + alloc((size_t)N * HID));          // fp8: 6.4 MB
    uint_t*   posq  = (uint_t*)  (base + alloc((size_t)N * HID));          // fp8
    uint_t*   negq  = (uint_t*)  (base + alloc((size_t)N * HID));          // fp8
    int2*     csrS  = (int2*)   (base + alloc(((size_t)NBUCK * PAD_PER + 64) * 8));
    int2*     ebuf  = (int2*)   (base + alloc((size_t)NBUCK * EBUF_PER * 8));
    int*      rowptr= (int*)    (base + alloc(((size_t)N + 1) * 4));
    float*    dinv  = (float*)  (base + alloc((size_t)N * 4));
    size_t zOff = alloc(NBUCK * 4 + 132 * 4);
    int*      bcur  = (int*)(base + zOff);
    float*    smallb= (float*)(base + zOff + NBUCK * 4);
    float* sumvec = smallb;

    int nbA = (E + CHUNK - 1) / CHUNK;    // 391
    int nbG = (N + 63) / 64;              // 1563
    int nbB = (N + 511) / 512;            // 196

    hipMemsetAsync(bcur, 0, NBUCK * 4 + 132 * 4, stream);
    k_fused<<<nbA + nbG, 256, 0, stream>>>(x, W_gcn, src, dst, Hq, bcur, ebuf, N, E, nbA);
    k_binB1<<<nbB, 256, 0, stream>>>(ebuf, bcur, rowptr, dinv, N);
    k_binB2<<<nbB, 256, 0, stream>>>(ebuf, bcur, rowptr, perm, dinv, csrS, N);
    k_gather<<<2048, 256, 0, stream>>>(Hq, rowptr, csrS, perm, dinv,
                                       b_gcn, prelu_a, posq, negq, sumvec, N);
    k_loss<<<512, 256, 0, stream>>>(posq, negq, smallb, W_disc, (float*)d_out, N);
}

// Round 21
// 200.724 us; speedup vs baseline: 1.3675x; 1.1274x over previous
//
#include <hip/hip_runtime.h>

#define HID 64
#define INDIM 128
#define NBUCK 256          // bucket = dst >> 9  (512 nodes/bucket)
#define EBUF_PER 10240     // fixed ebuf region per bucket (raw, 22 sigma)
#define PAD_PER 14336      // fixed padded csr region per bucket
#define CHUNK 4096         // edges per binA block
#define RMASK 0x1FFFFu     // row-index mask (fault-safety for unconsumed loads)

typedef unsigned short ushort_t;
typedef unsigned int uint_t;
typedef float floatx2 __attribute__((ext_vector_type(2)));

__device__ __forceinline__ float softplusf(float x) {
    return fmaxf(x, 0.f) + log1pf(expf(-fabsf(x)));
}
__device__ __forceinline__ float dec_norm(uint_t x) {
    union { uint_t i; float f; } c; c.i = (x >> 17) << 16; return c.f;
}

// ===== K1: fused [binA (blocks 0..nbA) | gemm (rest)] ======================
__global__ __launch_bounds__(256) void k_fused(const float* __restrict__ x,
                                               const float* __restrict__ W,
                                               const int* __restrict__ src,
                                               const int* __restrict__ dst,
                                               uint_t* __restrict__ Hq,
                                               int* __restrict__ bcur,
                                               int2* __restrict__ ebuf,
                                               int N, int E, int nbA) {
    __shared__ char lds[66560];
    int tid = threadIdx.x;

    if ((int)blockIdx.x < nbA) {
        // ---------------- binA ----------------
        int2* stage  = (int2*)lds;               // 32768
        int* lcnt    = (int*)(lds + 32768);
        int* binSt   = (int*)(lds + 33792);
        int* lofs    = (int*)(lds + 34816);
        int* gofs    = (int*)(lds + 35840);
        int* scn     = (int*)(lds + 36864);      // ..37888
        int base = blockIdx.x * CHUNK;

        lcnt[tid] = 0;
        __syncthreads();

        int sv[16], dv[16];
#pragma unroll
        for (int i = 0; i < 16; i++) {
            int e = base + i * 256 + tid;
            if (e < E) { sv[i] = src[e]; dv[i] = dst[e]; }
            else dv[i] = -1;
        }
#pragma unroll
        for (int i = 0; i < 16; i++)
            if (dv[i] >= 0) atomicAdd(&lcnt[dv[i] >> 9], 1);
        __syncthreads();

        scn[tid] = lcnt[tid];
        __syncthreads();
        for (int off = 1; off < NBUCK; off <<= 1) {
            int v = (tid >= off) ? scn[tid - off] : 0;
            __syncthreads();
            scn[tid] += v;
            __syncthreads();
        }
        binSt[tid] = scn[tid] - lcnt[tid];
        lofs[tid] = binSt[tid];
        __syncthreads();

#pragma unroll
        for (int i = 0; i < 16; i++) {
            if (dv[i] >= 0) {
                int b = dv[i] >> 9;
                int p = atomicAdd(&lofs[b], 1);
                stage[p] = make_int2(sv[i], dv[i]);
            }
        }
        __syncthreads();

        if (lcnt[tid] > 0)
            gofs[tid] = tid * EBUF_PER + atomicAdd(&bcur[tid], lcnt[tid]);
        __syncthreads();

        int total = (base + CHUNK <= E) ? CHUNK : (E > base ? E - base : 0);
        for (int idx = tid; idx < total; idx += 256) {
            int2 v = stage[idx];
            int b = v.y >> 9;
            ebuf[gofs[b] + (idx - binSt[b])] = v;
        }
    } else {
        // ------- gemm: 64 rows, acc[4][4], float4 LDS reads ----------------
        float* Xs = (float*)lds;                 // 64*132*4 = 33792
        float* Ws = (float*)(lds + 33792);       // 32768 -> total 66560
        int row0 = ((int)blockIdx.x - nbA) * 64;

        const float4* W4 = (const float4*)W;
        float4* Ws4 = (float4*)Ws;
#pragma unroll
        for (int i = 0; i < 8; i++) Ws4[tid + 256 * i] = W4[tid + 256 * i];

#pragma unroll
        for (int i = 0; i < 8; i++) {
            int j = tid + 256 * i;
            int r = j >> 5, c4 = j & 31;
            int row = row0 + r;
            float4 v = make_float4(0.f, 0.f, 0.f, 0.f);
            if (row < N) v = *(const float4*)(x + (size_t)row * INDIM + c4 * 4);
            *(float4*)(&Xs[r * 132 + c4 * 4]) = v;
        }
        __syncthreads();

        int tx = tid & 15;
        int ty = tid >> 4;
        float acc[4][4] = {};
        const float* xa = &Xs[(ty * 4) * 132];
#pragma unroll 4
        for (int k4 = 0; k4 < 32; k4++) {
            float4 x0 = *(const float4*)(&xa[k4 * 4]);
            float4 x1 = *(const float4*)(&xa[132 + k4 * 4]);
            float4 x2 = *(const float4*)(&xa[264 + k4 * 4]);
            float4 x3 = *(const float4*)(&xa[396 + k4 * 4]);
#pragma unroll
            for (int kk = 0; kk < 4; kk++) {
                float4 bv = *(const float4*)(&Ws[(k4 * 4 + kk) * 64 + tx * 4]);
                float a0 = ((const float*)&x0)[kk];
                float a1 = ((const float*)&x1)[kk];
                float a2 = ((const float*)&x2)[kk];
                float a3 = ((const float*)&x3)[kk];
                acc[0][0] = fmaf(a0, bv.x, acc[0][0]);
                acc[0][1] = fmaf(a0, bv.y, acc[0][1]);
                acc[0][2] = fmaf(a0, bv.z, acc[0][2]);
                acc[0][3] = fmaf(a0, bv.w, acc[0][3]);
                acc[1][0] = fmaf(a1, bv.x, acc[1][0]);
                acc[1][1] = fmaf(a1, bv.y, acc[1][1]);
                acc[1][2] = fmaf(a1, bv.z, acc[1][2]);
                acc[1][3] = fmaf(a1, bv.w, acc[1][3]);
                acc[2][0] = fmaf(a2, bv.x, acc[2][0]);
                acc[2][1] = fmaf(a2, bv.y, acc[2][1]);
                acc[2][2] = fmaf(a2, bv.z, acc[2][2]);
                acc[2][3] = fmaf(a2, bv.w, acc[2][3]);
                acc[3][0] = fmaf(a3, bv.x, acc[3][0]);
                acc[3][1] = fmaf(a3, bv.y, acc[3][1]);
                acc[3][2] = fmaf(a3, bv.z, acc[3][2]);
                acc[3][3] = fmaf(a3, bv.w, acc[3][3]);
            }
        }
#pragma unroll
        for (int i = 0; i < 4; i++) {
            int row = row0 + ty * 4 + i;
            if (row < N) {
                uint_t u = 0;
                u = __builtin_amdgcn_cvt_pk_fp8_f32(acc[i][0], acc[i][1], u, false);
                u = __builtin_amdgcn_cvt_pk_fp8_f32(acc[i][2], acc[i][3], u, true);
                Hq[(size_t)row * 16 + tx] = u;
            }
        }
    }
}

// ===== K2: HC build — HC[n] = { Hq[n] (16 u32) | Hq[perm[n]] (16 u32) } ====
__global__ __launch_bounds__(256) void k_hc(const uint_t* __restrict__ Hq,
                                            const int* __restrict__ perm,
                                            uint_t* __restrict__ HC, int N) {
    int g = blockIdx.x * 256 + threadIdx.x;     // over N*16
    if (g >= N * 16) return;
    int n = g >> 4, sub = g & 15;
    HC[(size_t)n * 32 + sub] = Hq[(size_t)n * 16 + sub];
    HC[(size_t)n * 32 + 16 + sub] = Hq[(size_t)perm[n] * 16 + sub];
}

// ===== K3: binB1 — per-bucket degrees -> packed padded rowptr, dinv ========
__global__ __launch_bounds__(256) void k_binB1(const int2* __restrict__ ebuf,
                                               const int* __restrict__ bcur,
                                               int* __restrict__ rowptr,
                                               float* __restrict__ dinvg,
                                               int N) {
    __shared__ int sc[256];
    __shared__ int ldeg[512];
    int tid = threadIdx.x;
    int b = blockIdx.x;

    ldeg[tid] = 0;
    ldeg[tid + 256] = 0;
    __syncthreads();

    int start = b * EBUF_PER;
    int cb = bcur[b];
    for (int i = start + tid; i < start + cb; i += 256)
        atomicAdd(&ldeg[ebuf[i].y & 511], 1);
    __syncthreads();

    int d0 = ldeg[2 * tid], d1 = ldeg[2 * tid + 1];
    int p0 = (d0 + 7) & ~7, p1 = (d1 + 7) & ~7;
    int s2 = p0 + p1;
    sc[tid] = s2;
    __syncthreads();
    for (int off = 1; off < 256; off <<= 1) {
        int v = (tid >= off) ? sc[tid - off] : 0;
        __syncthreads();
        sc[tid] += v;
        __syncthreads();
    }
    int ex = sc[tid] - s2;
    int n0 = (b << 9) + 2 * tid, n1 = n0 + 1;
    int prow0 = b * PAD_PER + ex;
    int prow1 = prow0 + p0;
    if (n0 < N) { rowptr[n0] = prow0 | ((p0 >> 3) << 23); dinvg[n0] = rsqrtf((float)(d0 + 1)); }
    if (n1 < N) { rowptr[n1] = prow1 | ((p1 >> 3) << 23); dinvg[n1] = rsqrtf((float)(d1 + 1)); }
}

// ===== K4: binB2 — placement: csrS[j] = u32 { s | norm15<<17 } + pad fill ==
__global__ __launch_bounds__(256) void k_binB2(const int2* __restrict__ ebuf,
                                               const int* __restrict__ bcur,
                                               const int* __restrict__ rowptr,
                                               const float* __restrict__ dinvg,
                                               uint_t* __restrict__ csrS, int N) {
    __shared__ int lcur[512];
    __shared__ float ldinv[512];
    int tid = threadIdx.x;
    int b = blockIdx.x;
    int nodeBase = b << 9;
    for (int i = tid; i < 512; i += 256) {
        int n = nodeBase + i;
        lcur[i] = (n < N) ? (rowptr[n] & 0x7FFFFF) : 0;
        ldinv[i] = (n < N) ? dinvg[n] : 0.f;
    }
    __syncthreads();

    int start = b * EBUF_PER;
    int cb = bcur[b];
    for (int i = start + tid; i < start + cb; i += 256) {
        int2 v = ebuf[i];
        int s = v.x, dl = v.y & 511;
        int j = atomicAdd(&lcur[dl], 1);
        float nm = dinvg[s] * ldinv[dl];
        union { float f; uint_t u; } cu; cu.f = nm;
        uint_t nb = (cu.u >> 16) & 0x7FFFu;
        csrS[j] = (uint_t)s | (nb << 17);
    }
    __syncthreads();

    for (int i = tid; i < 512; i += 256) {
        int n = nodeBase + i;
        if (n < N) {
            uint_t r = (uint_t)rowptr[n];
            int e = (int)(r & 0x7FFFFF) + 8 * (int)(r >> 23);
            for (int j = lcur[i]; j < e; j++) csrS[j] = 0u;
        }
    }
}

// ===== K5: gather — paired-view HC records (128 B/edge), branchless ========
// lane = (slot, sub16); slot = (pair, isneg). One edge = one 128-B record:
// HC[s*32 + isneg*16 + sub]. One wave load = 2 edges x 128 B contiguous.
__global__ __launch_bounds__(256) void k_gather(const uint_t* __restrict__ HC,
                                                const int* __restrict__ rowptr,
                                                const uint_t* __restrict__ csrS,
                                                const float* __restrict__ dinv,
                                                const float* __restrict__ b,
                                                const float* __restrict__ a,
                                                uint_t* __restrict__ posq,
                                                uint_t* __restrict__ negq,
                                                float* __restrict__ sumvec, int N) {
    int tid = threadIdx.x;
    int lane = tid & 63;
    int slot = lane >> 4;
    int sub = lane & 15;
    int isneg = slot & 1;
    int pair = slot >> 1;
    int hoff = isneg * 16 + sub;                 // word offset within HC record
    int wid = (blockIdx.x * 256 + tid) >> 6;
    int nw = gridDim.x * 4;
    float4 b4 = ((const float4*)b)[sub];
    float4 a4 = ((const float4*)a)[sub];
    float s0 = 0.f, s1 = 0.f, s2 = 0.f, s3 = 0.f;

    for (int n = wid; n < N; n += nw) {
        float dv = dinv[n];
        float w2 = dv * dv;
        uint_t r = (uint_t)rowptr[n];
        int beg = (int)(r & 0x7FFFFF);
        int iters = (int)(r >> 23);
        float a0 = 0.f, a1 = 0.f, a2 = 0.f, a3 = 0.f;

        int base0 = beg + pair;
        uint_t cA0 = csrS[base0];
        uint_t cA1 = csrS[base0 + 2];
        uint_t cA2 = csrS[base0 + 4];
        uint_t cA3 = csrS[base0 + 6];
        uint_t cB0 = csrS[base0 + 8];
        uint_t cB1 = csrS[base0 + 10];
        uint_t cB2 = csrS[base0 + 12];
        uint_t cB3 = csrS[base0 + 14];
        uint_t uc0 = HC[(size_t)(cA0 & RMASK) * 32 + hoff];
        uint_t uc1 = HC[(size_t)(cA1 & RMASK) * 32 + hoff];
        uint_t uc2 = HC[(size_t)(cA2 & RMASK) * 32 + hoff];
        uint_t uc3 = HC[(size_t)(cA3 & RMASK) * 32 + hoff];

        for (int it = 0; it < iters; it++) {
            int gbase = base0 + (it + 2) * 8;
            uint_t cC0 = csrS[gbase];
            uint_t cC1 = csrS[gbase + 2];
            uint_t cC2 = csrS[gbase + 4];
            uint_t cC3 = csrS[gbase + 6];
            uint_t un0 = HC[(size_t)(cB0 & RMASK) * 32 + hoff];
            uint_t un1 = HC[(size_t)(cB1 & RMASK) * 32 + hoff];
            uint_t un2 = HC[(size_t)(cB2 & RMASK) * 32 + hoff];
            uint_t un3 = HC[(size_t)(cB3 & RMASK) * 32 + hoff];
            float mA0 = dec_norm(cA0);
            float mA1 = dec_norm(cA1);
            float mA2 = dec_norm(cA2);
            float mA3 = dec_norm(cA3);
            floatx2 lo, hi;
            lo = __builtin_amdgcn_cvt_pk_f32_fp8(uc0, false);
            hi = __builtin_amdgcn_cvt_pk_f32_fp8(uc0, true);
            a0 = fmaf(lo.x, mA0, a0); a1 = fmaf(lo.y, mA0, a1);
            a2 = fmaf(hi.x, mA0, a2); a3 = fmaf(hi.y, mA0, a3);
            lo = __builtin_amdgcn_cvt_pk_f32_fp8(uc1, false);
            hi = __builtin_amdgcn_cvt_pk_f32_fp8(uc1, true);
            a0 = fmaf(lo.x, mA1, a0); a1 = fmaf(lo.y, mA1, a1);
            a2 = fmaf(hi.x, mA1, a2); a3 = fmaf(hi.y, mA1, a3);
            lo = __builtin_amdgcn_cvt_pk_f32_fp8(uc2, false);
            hi = __builtin_amdgcn_cvt_pk_f32_fp8(uc2, true);
            a0 = fmaf(lo.x, mA2, a0); a1 = fmaf(lo.y, mA2, a1);
            a2 = fmaf(hi.x, mA2, a2); a3 = fmaf(hi.y, mA2, a3);
            lo = __builtin_amdgcn_cvt_pk_f32_fp8(uc3, false);
            hi = __builtin_amdgcn_cvt_pk_f32_fp8(uc3, true);
            a0 = fmaf(lo.x, mA3, a0); a1 = fmaf(lo.y, mA3, a1);
            a2 = fmaf(hi.x, mA3, a2); a3 = fmaf(hi.y, mA3, a3);
            cA0 = cB0; cA1 = cB1; cA2 = cB2; cA3 = cB3;
            cB0 = cC0; cB1 = cC1; cB2 = cC2; cB3 = cC3;
            uc0 = un0; uc1 = un1; uc2 = un2; uc3 = un3;
        }
        a0 += __shfl_xor(a0, 32);
        a1 += __shfl_xor(a1, 32);
        a2 += __shfl_xor(a2, 32);
        a3 += __shfl_xor(a3, 32);
        // self-loop: record n, view isneg (HC[n][16:32] = Hq[perm[n]])
        uint_t us = HC[(size_t)n * 32 + hoff];
        floatx2 slo = __builtin_amdgcn_cvt_pk_f32_fp8(us, false);
        floatx2 shi = __builtin_amdgcn_cvt_pk_f32_fp8(us, true);
        float v0 = fmaf(slo.x, w2, a0) + b4.x;
        float v1 = fmaf(slo.y, w2, a1) + b4.y;
        float v2 = fmaf(shi.x, w2, a2) + b4.z;
        float v3 = fmaf(shi.y, w2, a3) + b4.w;
        v0 = v0 > 0.f ? v0 : v0 * a4.x;
        v1 = v1 > 0.f ? v1 : v1 * a4.y;
        v2 = v2 > 0.f ? v2 : v2 * a4.z;
        v3 = v3 > 0.f ? v3 : v3 * a4.w;
        if (lane < 32) {
            uint_t pk = 0;
            pk = __builtin_amdgcn_cvt_pk_fp8_f32(v0, v1, pk, false);
            pk = __builtin_amdgcn_cvt_pk_fp8_f32(v2, v3, pk, true);
            uint_t* outp = isneg ? negq : posq;
            outp[(size_t)n * 16 + sub] = pk;
            if (!isneg) { s0 += v0; s1 += v1; s2 += v2; s3 += v3; }
        }
    }

    __shared__ float red[4][64];
    int w = tid >> 6;
    if (slot == 0) {
        red[w][sub * 4 + 0] = s0;
        red[w][sub * 4 + 1] = s1;
        red[w][sub * 4 + 2] = s2;
        red[w][sub * 4 + 3] = s3;
    }
    __syncthreads();
    if (tid < 64) {
        float s = red[0][tid] + red[1][tid] + red[2][tid] + red[3][tid];
        atomicAdd(&sumvec[tid], s);
    }
}

// ===== K6: loss — fp8 pos/neg, 2 nodes/wave-iter, disc fused, final ========
__global__ __launch_bounds__(256) void k_loss(const uint_t* __restrict__ posq,
                                              const uint_t* __restrict__ negq,
                                              float* __restrict__ smallb,
                                              const float* __restrict__ Wd,
                                              float* __restrict__ out, int N) {
    __shared__ float summ[64];
    __shared__ float svecS[64];
    __shared__ float redL[4][4];
    int tid = threadIdx.x;
    float* sumvec = smallb;
    float* lossAcc = smallb + 128;
    int* done = (int*)(smallb + 129);

    if (tid < 64) summ[tid] = 1.f / (1.f + expf(-sumvec[tid] / (float)N));
    __syncthreads();
    if (tid < 64) {
        float s = 0.f;
#pragma unroll
        for (int j = 0; j < 64; j++) s += Wd[tid * 64 + j] * summ[j];
        svecS[tid] = s;
    }
    __syncthreads();

    int lane = tid & 63;
    int slot = lane >> 4;
    int sub = lane & 15;
    int isneg = slot & 1;
    int pair = slot >> 1;
    int w = tid >> 6;
    float4 sv = ((const float4*)svecS)[sub];
    const uint_t* Pb = isneg ? negq : posq;
    float l = 0.f;
    int wid = (blockIdx.x * 256 + tid) >> 6;
    int nw = gridDim.x * 4;
    for (int g = wid; 2 * g < N; g += nw) {
        int row = 2 * g + pair;
        bool valid = row < N;
        uint_t u = valid ? Pb[(size_t)row * 16 + sub] : 0u;
        floatx2 lo = __builtin_amdgcn_cvt_pk_f32_fp8(u, false);
        floatx2 hi = __builtin_amdgcn_cvt_pk_f32_fp8(u, true);
        float p = lo.x * sv.x + lo.y * sv.y + hi.x * sv.z + hi.y * sv.w;
        p += __shfl_xor(p, 1);
        p += __shfl_xor(p, 2);
        p += __shfl_xor(p, 4);
        p += __shfl_xor(p, 8);
        if (sub == 0 && valid) l += isneg ? softplusf(p) : softplusf(-p);
    }
    if (sub == 0) redL[w][slot] = l;
    __syncthreads();
    if (tid == 0) {
        float t = 0.f;
#pragma unroll
        for (int i = 0; i < 4; i++)
#pragma unroll
            for (int j = 0; j < 4; j++) t += redL[i][j];
        atomicAdd(&lossAcc[0], t);
        __threadfence();
        int old = atomicAdd(done, 1);
        if (old == (int)gridDim.x - 1) {
            float tot = atomicAdd(&lossAcc[0], 0.f);
            out[0] = tot / (float)N;
        }
    }
}

extern "C" void kernel_launch(void* const* d_in, const int* in_sizes, int n_in,
                              void* d_out, int out_size, void* d_ws, size_t ws_size,
                              hipStream_t stream) {
    const float* x      = (const float*)d_in[0];
    const float* W_gcn  = (const float*)d_in[1];
    const float* b_gcn  = (const float*)d_in[2];
    const float* prelu_a= (const float*)d_in[3];
    const float* W_disc = (const float*)d_in[4];
    const int*   eidx   = (const int*)d_in[5];
    const int*   perm   = (const int*)d_in[6];

    int N = in_sizes[0] / INDIM;      // 100000
    int E = in_sizes[5] / 2;          // 1600000
    const int* src = eidx;
    const int* dst = eidx + E;

    char* base = (char*)d_ws;
    size_t off = 0;
    auto alloc = [&](size_t bytes) { size_t o = off; off = (off + bytes + 255) & ~(size_t)255; return o; };
    uint_t*   Hq    = (uint_t*)  (base + alloc((size_t)N * HID));              // fp8: 6.4 MB
    // HC sized for RMASK over-reads: (0x1FFFF*32 + 32) u32 ≈ 16.8 MB
    uint_t*   HC    = (uint_t*)  (base + alloc(((size_t)0x20000 * 32) * 4));
    uint_t*   posq  = (uint_t*)  (base + alloc((size_t)N * HID));              // fp8
    uint_t*   negq  = (uint_t*)  (base + alloc((size_t)N * HID));              // fp8
    uint_t*   csrS  = (uint_t*)  (base + alloc(((size_t)NBUCK * PAD_PER + 64) * 4));
    int2*     ebuf  = (int2*)   (base + alloc((size_t)NBUCK * EBUF_PER * 8));
    int*      rowptr= (int*)    (base + alloc(((size_t)N + 1) * 4));
    float*    dinv  = (float*)  (base + alloc((size_t)N * 4));
    size_t zOff = alloc(NBUCK * 4 + 132 * 4);
    int*      bcur  = (int*)(base + zOff);
    float*    smallb= (float*)(base + zOff + NBUCK * 4);
    float* sumvec = smallb;

    int nbA = (E + CHUNK - 1) / CHUNK;    // 391
    int nbG = (N + 63) / 64;              // 1563
    int nbB = (N + 511) / 512;            // 196
    int nbH = (N * 16 + 255) / 256;       // 6250

    hipMemsetAsync(bcur, 0, NBUCK * 4 + 132 * 4, stream);
    k_fused<<<nbA + nbG, 256, 0, stream>>>(x, W_gcn, src, dst, Hq, bcur, ebuf, N, E, nbA);
    k_hc<<<nbH, 256, 0, stream>>>(Hq, perm, HC, N);
    k_binB1<<<nbB, 256, 0, stream>>>(ebuf, bcur, rowptr, dinv, N);
    k_binB2<<<nbB, 256, 0, stream>>>(ebuf, bcur, rowptr, dinv, csrS, N);
    k_gather<<<2048, 256, 0, stream>>>(HC, rowptr, csrS, dinv,
                                       b_gcn, prelu_a, posq, negq, sumvec, N);
    k_loss<<<512, 256, 0, stream>>>(posq, negq, smallb, W_disc, (float*)d_out, N);
}

// Round 22
// 183.247 us; speedup vs baseline: 1.4979x; 1.0954x over previous
//
#include <hip/hip_runtime.h>

#define HID 64
#define INDIM 128
#define NBUCK 256          // bucket = dst >> 9  (512 nodes/bucket)
#define EBUF_PER 10240     // fixed ebuf region per bucket (raw, 22 sigma)
#define PAD_PER 14336      // fixed padded csr region per bucket
#define CHUNK 4096         // edges per binA block
#define RMASK 0x1FFFFu     // row-index mask (fault-safety for unconsumed loads)

typedef unsigned short ushort_t;
typedef unsigned int uint_t;
typedef float floatx2 __attribute__((ext_vector_type(2)));
typedef short bf16x8 __attribute__((ext_vector_type(8)));
typedef float f32x4 __attribute__((ext_vector_type(4)));

__device__ __forceinline__ float softplusf(float x) {
    return fmaxf(x, 0.f) + log1pf(expf(-fabsf(x)));
}
__device__ __forceinline__ ushort_t f2bf(float f) {
    union { float f; uint_t i; } c; c.f = f;
    uint_t u = c.i;
    u += 0x7FFFu + ((u >> 16) & 1u);
    return (ushort_t)(u >> 16);
}
__device__ __forceinline__ float dec_norm(uint_t x) {
    union { uint_t i; float f; } c; c.i = (x >> 17) << 16; return c.f;
}

// ===== K1: fused [binA (blocks 0..nbA) | MFMA gemm (rest)] =================
__global__ __launch_bounds__(256) void k_fused(const float* __restrict__ x,
                                               const float* __restrict__ W,
                                               const int* __restrict__ src,
                                               const int* __restrict__ dst,
                                               uint_t* __restrict__ Hq,
                                               int* __restrict__ bcur,
                                               int2* __restrict__ ebuf,
                                               int N, int E, int nbA) {
    __shared__ char lds[37888];
    int tid = threadIdx.x;

    if ((int)blockIdx.x < nbA) {
        // ---------------- binA ----------------
        int2* stage  = (int2*)lds;               // 32768
        int* lcnt    = (int*)(lds + 32768);
        int* binSt   = (int*)(lds + 33792);
        int* lofs    = (int*)(lds + 34816);
        int* gofs    = (int*)(lds + 35840);
        int* scn     = (int*)(lds + 36864);      // ..37888
        int base = blockIdx.x * CHUNK;

        lcnt[tid] = 0;
        __syncthreads();

        int sv[16], dv[16];
#pragma unroll
        for (int i = 0; i < 16; i++) {
            int e = base + i * 256 + tid;
            if (e < E) { sv[i] = src[e]; dv[i] = dst[e]; }
            else dv[i] = -1;
        }
#pragma unroll
        for (int i = 0; i < 16; i++)
            if (dv[i] >= 0) atomicAdd(&lcnt[dv[i] >> 9], 1);
        __syncthreads();

        scn[tid] = lcnt[tid];
        __syncthreads();
        for (int off = 1; off < NBUCK; off <<= 1) {
            int v = (tid >= off) ? scn[tid - off] : 0;
            __syncthreads();
            scn[tid] += v;
            __syncthreads();
        }
        binSt[tid] = scn[tid] - lcnt[tid];
        lofs[tid] = binSt[tid];
        __syncthreads();

#pragma unroll
        for (int i = 0; i < 16; i++) {
            if (dv[i] >= 0) {
                int b = dv[i] >> 9;
                int p = atomicAdd(&lofs[b], 1);
                stage[p] = make_int2(sv[i], dv[i]);
            }
        }
        __syncthreads();

        if (lcnt[tid] > 0)
            gofs[tid] = tid * EBUF_PER + atomicAdd(&bcur[tid], lcnt[tid]);
        __syncthreads();

        int total = (base + CHUNK <= E) ? CHUNK : (E > base ? E - base : 0);
        for (int idx = tid; idx < total; idx += 256) {
            int2 v = stage[idx];
            int b = v.y >> 9;
            ebuf[gofs[b] + (idx - binSt[b])] = v;
        }
    } else {
        // ------- MFMA gemm: 64 rows x 64 cols, bf16 in, fp8 out ------------
        ushort_t* Wt = (ushort_t*)lds;                 // [64][136] bf16 = 17408
        ushort_t* Xs = (ushort_t*)(lds + 17408);       // [64][136] bf16 = 17408
        float*    Cs = (float*)(lds + 17408);          // aliases Xs post-compute
        int row0 = ((int)blockIdx.x - nbA) * 64;

        // stage W -> Wt transposed bf16 (pad stride 136 kills bank conflicts)
        const float4* W4 = (const float4*)W;
#pragma unroll
        for (int i = 0; i < 8; i++) {
            int idx4 = tid + 256 * i;                  // 2048 float4s
            float4 v = W4[idx4];
            int gidx = idx4 * 4;
            int k = gidx >> 6, c = gidx & 63;
            Wt[(c + 0) * 136 + k] = f2bf(v.x);
            Wt[(c + 1) * 136 + k] = f2bf(v.y);
            Wt[(c + 2) * 136 + k] = f2bf(v.z);
            Wt[(c + 3) * 136 + k] = f2bf(v.w);
        }
        // stage x-tile -> Xs bf16 (coalesced float4 reads)
#pragma unroll
        for (int i = 0; i < 8; i++) {
            int idx4 = tid + 256 * i;                  // 2048 float4s
            int gidx = idx4 * 4;
            int r = gidx >> 7, k = gidx & 127;
            int row = row0 + r;
            float4 v = make_float4(0.f, 0.f, 0.f, 0.f);
            if (row < N) v = *(const float4*)(x + (size_t)row * INDIM + k);
            ushort4 o;
            o.x = f2bf(v.x); o.y = f2bf(v.y); o.z = f2bf(v.z); o.w = f2bf(v.w);
            *(ushort4*)(&Xs[r * 136 + k]) = o;
        }
        __syncthreads();

        int wv = tid >> 6, l = tid & 63;
        int lr = l & 15, kb = l >> 4;
        int arow = wv * 16 + lr;
        f32x4 acc0 = {0.f, 0.f, 0.f, 0.f};
        f32x4 acc1 = {0.f, 0.f, 0.f, 0.f};
        f32x4 acc2 = {0.f, 0.f, 0.f, 0.f};
        f32x4 acc3 = {0.f, 0.f, 0.f, 0.f};
#pragma unroll
        for (int ks = 0; ks < 4; ks++) {
            int k0 = ks * 32 + kb * 8;
            bf16x8 af = *(const bf16x8*)(&Xs[arow * 136 + k0]);
            bf16x8 b0 = *(const bf16x8*)(&Wt[(0 * 16 + lr) * 136 + k0]);
            bf16x8 b1 = *(const bf16x8*)(&Wt[(1 * 16 + lr) * 136 + k0]);
            bf16x8 b2 = *(const bf16x8*)(&Wt[(2 * 16 + lr) * 136 + k0]);
            bf16x8 b3 = *(const bf16x8*)(&Wt[(3 * 16 + lr) * 136 + k0]);
            acc0 = __builtin_amdgcn_mfma_f32_16x16x32_bf16(af, b0, acc0, 0, 0, 0);
            acc1 = __builtin_amdgcn_mfma_f32_16x16x32_bf16(af, b1, acc1, 0, 0, 0);
            acc2 = __builtin_amdgcn_mfma_f32_16x16x32_bf16(af, b2, acc2, 0, 0, 0);
            acc3 = __builtin_amdgcn_mfma_f32_16x16x32_bf16(af, b3, acc3, 0, 0, 0);
        }
        __syncthreads();   // Xs reads complete; region becomes Cs
        // C/D layout: col = lane&15, row = (lane>>4)*4 + reg  [m89-verified]
#pragma unroll
        for (int j = 0; j < 4; j++) {
            int crow = wv * 16 + (l >> 4) * 4 + j;
            Cs[crow * 64 + 0 * 16 + lr] = acc0[j];
            Cs[crow * 64 + 1 * 16 + lr] = acc1[j];
            Cs[crow * 64 + 2 * 16 + lr] = acc2[j];
            Cs[crow * 64 + 3 * 16 + lr] = acc3[j];
        }
        __syncthreads();
        // pack fp8 + store
#pragma unroll
        for (int i = 0; i < 4; i++) {
            int idx = tid + 256 * i;                   // 1024 u32 outputs
            int r = idx >> 4, c4 = idx & 15;
            int row = row0 + r;
            if (row < N) {
                float v0 = Cs[r * 64 + c4 * 4 + 0];
                float v1 = Cs[r * 64 + c4 * 4 + 1];
                float v2 = Cs[r * 64 + c4 * 4 + 2];
                float v3 = Cs[r * 64 + c4 * 4 + 3];
                uint_t u = 0;
                u = __builtin_amdgcn_cvt_pk_fp8_f32(v0, v1, u, false);
                u = __builtin_amdgcn_cvt_pk_fp8_f32(v2, v3, u, true);
                Hq[(size_t)row * 16 + c4] = u;
            }
        }
    }
}

// ===== K2: HC build — HC[n] = { Hq[n] (16 u32) | Hq[perm[n]] (16 u32) } ====
__global__ __launch_bounds__(256) void k_hc(const uint_t* __restrict__ Hq,
                                            const int* __restrict__ perm,
                                            uint_t* __restrict__ HC, int N) {
    int g = blockIdx.x * 256 + threadIdx.x;     // over N*16
    if (g >= N * 16) return;
    int n = g >> 4, sub = g & 15;
    HC[(size_t)n * 32 + sub] = Hq[(size_t)n * 16 + sub];
    HC[(size_t)n * 32 + 16 + sub] = Hq[(size_t)perm[n] * 16 + sub];
}

// ===== K3: binB1 — per-bucket degrees -> packed padded rowptr, dinv ========
__global__ __launch_bounds__(256) void k_binB1(const int2* __restrict__ ebuf,
                                               const int* __restrict__ bcur,
                                               int* __restrict__ rowptr,
                                               float* __restrict__ dinvg,
                                               int N) {
    __shared__ int sc[256];
    __shared__ int ldeg[512];
    int tid = threadIdx.x;
    int b = blockIdx.x;

    ldeg[tid] = 0;
    ldeg[tid + 256] = 0;
    __syncthreads();

    int start = b * EBUF_PER;
    int cb = bcur[b];
    for (int i = start + tid; i < start + cb; i += 256)
        atomicAdd(&ldeg[ebuf[i].y & 511], 1);
    __syncthreads();

    int d0 = ldeg[2 * tid], d1 = ldeg[2 * tid + 1];
    int p0 = (d0 + 7) & ~7, p1 = (d1 + 7) & ~7;
    int s2 = p0 + p1;
    sc[tid] = s2;
    __syncthreads();
    for (int off = 1; off < 256; off <<= 1) {
        int v = (tid >= off) ? sc[tid - off] : 0;
        __syncthreads();
        sc[tid] += v;
        __syncthreads();
    }
    int ex = sc[tid] - s2;
    int n0 = (b << 9) + 2 * tid, n1 = n0 + 1;
    int prow0 = b * PAD_PER + ex;
    int prow1 = prow0 + p0;
    if (n0 < N) { rowptr[n0] = prow0 | ((p0 >> 3) << 23); dinvg[n0] = rsqrtf((float)(d0 + 1)); }
    if (n1 < N) { rowptr[n1] = prow1 | ((p1 >> 3) << 23); dinvg[n1] = rsqrtf((float)(d1 + 1)); }
}

// ===== K4: binB2 — placement: csrS[j] = u32 { s | norm15<<17 } + pad fill ==
__global__ __launch_bounds__(256) void k_binB2(const int2* __restrict__ ebuf,
                                               const int* __restrict__ bcur,
                                               const int* __restrict__ rowptr,
                                               const float* __restrict__ dinvg,
                                               uint_t* __restrict__ csrS, int N) {
    __shared__ int lcur[512];
    __shared__ float ldinv[512];
    int tid = threadIdx.x;
    int b = blockIdx.x;
    int nodeBase = b << 9;
    for (int i = tid; i < 512; i += 256) {
        int n = nodeBase + i;
        lcur[i] = (n < N) ? (rowptr[n] & 0x7FFFFF) : 0;
        ldinv[i] = (n < N) ? dinvg[n] : 0.f;
    }
    __syncthreads();

    int start = b * EBUF_PER;
    int cb = bcur[b];
    for (int i = start + tid; i < start + cb; i += 256) {
        int2 v = ebuf[i];
        int s = v.x, dl = v.y & 511;
        int j = atomicAdd(&lcur[dl], 1);
        float nm = dinvg[s] * ldinv[dl];
        union { float f; uint_t u; } cu; cu.f = nm;
        uint_t nb = (cu.u >> 16) & 0x7FFFu;
        csrS[j] = (uint_t)s | (nb << 17);
    }
    __syncthreads();

    for (int i = tid; i < 512; i += 256) {
        int n = nodeBase + i;
        if (n < N) {
            uint_t r = (uint_t)rowptr[n];
            int e = (int)(r & 0x7FFFFF) + 8 * (int)(r >> 23);
            for (int j = lcur[i]; j < e; j++) csrS[j] = 0u;
        }
    }
}

// ===== K5: gather — paired-view HC records (128 B/edge), branchless ========
__global__ __launch_bounds__(256) void k_gather(const uint_t* __restrict__ HC,
                                                const int* __restrict__ rowptr,
                                                const uint_t* __restrict__ csrS,
                                                const float* __restrict__ dinv,
                                                const float* __restrict__ b,
                                                const float* __restrict__ a,
                                                uint_t* __restrict__ posq,
                                                uint_t* __restrict__ negq,
                                                float* __restrict__ sumvec, int N) {
    int tid = threadIdx.x;
    int lane = tid & 63;
    int slot = lane >> 4;
    int sub = lane & 15;
    int isneg = slot & 1;
    int pair = slot >> 1;
    int hoff = isneg * 16 + sub;                 // word offset within HC record
    int wid = (blockIdx.x * 256 + tid) >> 6;
    int nw = gridDim.x * 4;
    float4 b4 = ((const float4*)b)[sub];
    float4 a4 = ((const float4*)a)[sub];
    float s0 = 0.f, s1 = 0.f, s2 = 0.f, s3 = 0.f;

    for (int n = wid; n < N; n += nw) {
        float dv = dinv[n];
        float w2 = dv * dv;
        uint_t r = (uint_t)rowptr[n];
        int beg = (int)(r & 0x7FFFFF);
        int iters = (int)(r >> 23);
        float a0 = 0.f, a1 = 0.f, a2 = 0.f, a3 = 0.f;

        int base0 = beg + pair;
        uint_t cA0 = csrS[base0];
        uint_t cA1 = csrS[base0 + 2];
        uint_t cA2 = csrS[base0 + 4];
        uint_t cA3 = csrS[base0 + 6];
        uint_t cB0 = csrS[base0 + 8];
        uint_t cB1 = csrS[base0 + 10];
        uint_t cB2 = csrS[base0 + 12];
        uint_t cB3 = csrS[base0 + 14];
        uint_t uc0 = HC[(size_t)(cA0 & RMASK) * 32 + hoff];
        uint_t uc1 = HC[(size_t)(cA1 & RMASK) * 32 + hoff];
        uint_t uc2 = HC[(size_t)(cA2 & RMASK) * 32 + hoff];
        uint_t uc3 = HC[(size_t)(cA3 & RMASK) * 32 + hoff];

        for (int it = 0; it < iters; it++) {
            int gbase = base0 + (it + 2) * 8;
            uint_t cC0 = csrS[gbase];
            uint_t cC1 = csrS[gbase + 2];
            uint_t cC2 = csrS[gbase + 4];
            uint_t cC3 = csrS[gbase + 6];
            uint_t un0 = HC[(size_t)(cB0 & RMASK) * 32 + hoff];
            uint_t un1 = HC[(size_t)(cB1 & RMASK) * 32 + hoff];
            uint_t un2 = HC[(size_t)(cB2 & RMASK) * 32 + hoff];
            uint_t un3 = HC[(size_t)(cB3 & RMASK) * 32 + hoff];
            float mA0 = dec_norm(cA0);
            float mA1 = dec_norm(cA1);
            float mA2 = dec_norm(cA2);
            float mA3 = dec_norm(cA3);
            floatx2 lo, hi;
            lo = __builtin_amdgcn_cvt_pk_f32_fp8(uc0, false);
            hi = __builtin_amdgcn_cvt_pk_f32_fp8(uc0, true);
            a0 = fmaf(lo.x, mA0, a0); a1 = fmaf(lo.y, mA0, a1);
            a2 = fmaf(hi.x, mA0, a2); a3 = fmaf(hi.y, mA0, a3);
            lo = __builtin_amdgcn_cvt_pk_f32_fp8(uc1, false);
            hi = __builtin_amdgcn_cvt_pk_f32_fp8(uc1, true);
            a0 = fmaf(lo.x, mA1, a0); a1 = fmaf(lo.y, mA1, a1);
            a2 = fmaf(hi.x, mA1, a2); a3 = fmaf(hi.y, mA1, a3);
            lo = __builtin_amdgcn_cvt_pk_f32_fp8(uc2, false);
            hi = __builtin_amdgcn_cvt_pk_f32_fp8(uc2, true);
            a0 = fmaf(lo.x, mA2, a0); a1 = fmaf(lo.y, mA2, a1);
            a2 = fmaf(hi.x, mA2, a2); a3 = fmaf(hi.y, mA2, a3);
            lo = __builtin_amdgcn_cvt_pk_f32_fp8(uc3, false);
            hi = __builtin_amdgcn_cvt_pk_f32_fp8(uc3, true);
            a0 = fmaf(lo.x, mA3, a0); a1 = fmaf(lo.y, mA3, a1);
            a2 = fmaf(hi.x, mA3, a2); a3 = fmaf(hi.y, mA3, a3);
            cA0 = cB0; cA1 = cB1; cA2 = cB2; cA3 = cB3;
            cB0 = cC0; cB1 = cC1; cB2 = cC2; cB3 = cC3;
            uc0 = un0; uc1 = un1; uc2 = un2; uc3 = un3;
        }
        a0 += __shfl_xor(a0, 32);
        a1 += __shfl_xor(a1, 32);
        a2 += __shfl_xor(a2, 32);
        a3 += __shfl_xor(a3, 32);
        uint_t us = HC[(size_t)n * 32 + hoff];
        floatx2 slo = __builtin_amdgcn_cvt_pk_f32_fp8(us, false);
        floatx2 shi = __builtin_amdgcn_cvt_pk_f32_fp8(us, true);
        float v0 = fmaf(slo.x, w2, a0) + b4.x;
        float v1 = fmaf(slo.y, w2, a1) + b4.y;
        float v2 = fmaf(shi.x, w2, a2) + b4.z;
        float v3 = fmaf(shi.y, w2, a3) + b4.w;
        v0 = v0 > 0.f ? v0 : v0 * a4.x;
        v1 = v1 > 0.f ? v1 : v1 * a4.y;
        v2 = v2 > 0.f ? v2 : v2 * a4.z;
        v3 = v3 > 0.f ? v3 : v3 * a4.w;
        if (lane < 32) {
            uint_t pk = 0;
            pk = __builtin_amdgcn_cvt_pk_fp8_f32(v0, v1, pk, false);
            pk = __builtin_amdgcn_cvt_pk_fp8_f32(v2, v3, pk, true);
            uint_t* outp = isneg ? negq : posq;
            outp[(size_t)n * 16 + sub] = pk;
            if (!isneg) { s0 += v0; s1 += v1; s2 += v2; s3 += v3; }
        }
    }

    __shared__ float red[4][64];
    int w = tid >> 6;
    if (slot == 0) {
        red[w][sub * 4 + 0] = s0;
        red[w][sub * 4 + 1] = s1;
        red[w][sub * 4 + 2] = s2;
        red[w][sub * 4 + 3] = s3;
    }
    __syncthreads();
    if (tid < 64) {
        float s = red[0][tid] + red[1][tid] + red[2][tid] + red[3][tid];
        atomicAdd(&sumvec[tid], s);
    }
}

// ===== K6: loss — fp8 pos/neg, 2 nodes/wave-iter, disc fused, final ========
__global__ __launch_bounds__(256) void k_loss(const uint_t* __restrict__ posq,
                                              const uint_t* __restrict__ negq,
                                              float* __restrict__ smallb,
                                              const float* __restrict__ Wd,
                                              float* __restrict__ out, int N) {
    __shared__ float summ[64];
    __shared__ float svecS[64];
    __shared__ float redL[4][4];
    int tid = threadIdx.x;
    float* sumvec = smallb;
    float* lossAcc = smallb + 128;
    int* done = (int*)(smallb + 129);

    if (tid < 64) summ[tid] = 1.f / (1.f + expf(-sumvec[tid] / (float)N));
    __syncthreads();
    if (tid < 64) {
        float s = 0.f;
#pragma unroll
        for (int j = 0; j < 64; j++) s += Wd[tid * 64 + j] * summ[j];
        svecS[tid] = s;
    }
    __syncthreads();

    int lane = tid & 63;
    int slot = lane >> 4;
    int sub = lane & 15;
    int isneg = slot & 1;
    int pair = slot >> 1;
    int w = tid >> 6;
    float4 sv = ((const float4*)svecS)[sub];
    const uint_t* Pb = isneg ? negq : posq;
    float l = 0.f;
    int wid = (blockIdx.x * 256 + tid) >> 6;
    int nw = gridDim.x * 4;
    for (int g = wid; 2 * g < N; g += nw) {
        int row = 2 * g + pair;
        bool valid = row < N;
        uint_t u = valid ? Pb[(size_t)row * 16 + sub] : 0u;
        floatx2 lo = __builtin_amdgcn_cvt_pk_f32_fp8(u, false);
        floatx2 hi = __builtin_amdgcn_cvt_pk_f32_fp8(u, true);
        float p = lo.x * sv.x + lo.y * sv.y + hi.x * sv.z + hi.y * sv.w;
        p += __shfl_xor(p, 1);
        p += __shfl_xor(p, 2);
        p += __shfl_xor(p, 4);
        p += __shfl_xor(p, 8);
        if (sub == 0 && valid) l += isneg ? softplusf(p) : softplusf(-p);
    }
    if (sub == 0) redL[w][slot] = l;
    __syncthreads();
    if (tid == 0) {
        float t = 0.f;
#pragma unroll
        for (int i = 0; i < 4; i++)
#pragma unroll
            for (int j = 0; j < 4; j++) t += redL[i][j];
        atomicAdd(&lossAcc[0], t);
        __threadfence();
        int old = atomicAdd(done, 1);
        if (old == (int)gridDim.x - 1) {
            float tot = atomicAdd(&lossAcc[0], 0.f);
            out[0] = tot / (float)N;
        }
    }
}

extern "C" void kernel_launch(void* const* d_in, const int* in_sizes, int n_in,
                              void* d_out, int out_size, void* d_ws, size_t ws_size,
                              hipStream_t stream) {
    const float* x      = (const float*)d_in[0];
    const float* W_gcn  = (const float*)d_in[1];
    const float* b_gcn  = (const float*)d_in[2];
    const float* prelu_a= (const float*)d_in[3];
    const float* W_disc = (const float*)d_in[4];
    const int*   eidx   = (const int*)d_in[5];
    const int*   perm   = (const int*)d_in[6];

    int N = in_sizes[0] / INDIM;      // 100000
    int E = in_sizes[5] / 2;          // 1600000
    const int* src = eidx;
    const int* dst = eidx + E;

    char* base = (char*)d_ws;
    size_t off = 0;
    auto alloc = [&](size_t bytes) { size_t o = off; off = (off + bytes + 255) & ~(size_t)255; return o; };
    uint_t*   Hq    = (uint_t*)  (base + alloc((size_t)N * HID));              // fp8: 6.4 MB
    uint_t*   HC    = (uint_t*)  (base + alloc(((size_t)0x20000 * 32) * 4));   // 16.8 MB
    uint_t*   posq  = (uint_t*)  (base + alloc((size_t)N * HID));              // fp8
    uint_t*   negq  = (uint_t*)  (base + alloc((size_t)N * HID));              // fp8
    uint_t*   csrS  = (uint_t*)  (base + alloc(((size_t)NBUCK * PAD_PER + 64) * 4));
    int2*     ebuf  = (int2*)   (base + alloc((size_t)NBUCK * EBUF_PER * 8));
    int*      rowptr= (int*)    (base + alloc(((size_t)N + 1) * 4));
    float*    dinv  = (float*)  (base + alloc((size_t)N * 4));
    size_t zOff = alloc(NBUCK * 4 + 132 * 4);
    int*      bcur  = (int*)(base + zOff);
    float*    smallb= (float*)(base + zOff + NBUCK * 4);
    float* sumvec = smallb;

    int nbA = (E + CHUNK - 1) / CHUNK;    // 391
    int nbG = (N + 63) / 64;              // 1563
    int nbB = (N + 511) / 512;            // 196
    int nbH = (N * 16 + 255) / 256;       // 6250

    hipMemsetAsync(bcur, 0, NBUCK * 4 + 132 * 4, stream);
    k_fused<<<nbA + nbG, 256, 0, stream>>>(x, W_gcn, src, dst, Hq, bcur, ebuf, N, E, nbA);
    k_hc<<<nbH, 256, 0, stream>>>(Hq, perm, HC, N);
    k_binB1<<<nbB, 256, 0, stream>>>(ebuf, bcur, rowptr, dinv, N);
    k_binB2<<<nbB, 256, 0, stream>>>(ebuf, bcur, rowptr, dinv, csrS, N);
    k_gather<<<2048, 256, 0, stream>>>(HC, rowptr, csrS, dinv,
                                       b_gcn, prelu_a, posq, negq, sumvec, N);
    k_loss<<<512, 256, 0, stream>>>(posq, negq, smallb, W_disc, (float*)d_out, N);
}